// Round 1
// baseline (3757.545 us; speedup 1.0000x reference)
//
#include <hip/hip_runtime.h>
#include <hip/hip_bf16.h>

#define NH 256      // H
#define NE 768      // E
#define NH2 512
#define NG3 768     // 3*H
#define NB 16
#define NLF 32
#define NBT 2048    // 4 fields * 16 * 32 rows
#define NTT 64      // tokens per side
#define NDE 2048

__device__ __forceinline__ float sigmoidf_(float x){ return 1.f/(1.f+expf(-x)); }
__device__ __forceinline__ float bflo_(unsigned int x){ return __uint_as_float(x<<16); }
__device__ __forceinline__ float bfhi_(unsigned int x){ return __uint_as_float(x & 0xffff0000u); }
__device__ __forceinline__ unsigned short f2bf_(float f){
  unsigned int x = __float_as_uint(f);
  unsigned int r = (x + 0x7fffu + ((x>>16)&1u)) >> 16;
  return (unsigned short)r;
}
// row in the (2048 x 512) embedding buffer for (side, b, tok)
__device__ __forceinline__ int tokrow(int side, int b, int tok){
  return (((side*2 + (tok>>5))*16 + b) << 5) + (tok & 31);
}

// ---------------- gather 4 fields into X0 (2048 x 768) ----------------
__global__ void k_gather(const float* __restrict__ f0, const float* __restrict__ f1,
                         const float* __restrict__ f2, const float* __restrict__ f3,
                         float* __restrict__ X0){
  int m = blockIdx.x;
  int f = m >> 9, rem = m & 511;
  const float* src = (f==0)? f0 : (f==1)? f1 : (f==2)? f2 : f3;
  const float* sp = src + (size_t)rem*NE;
  float* dp = X0 + (size_t)m*NE;
  for (int d = threadIdx.x; d < NE; d += 256) dp[d] = sp[d];
}

// ---------------- token & attribute masks ----------------
__global__ void k_masks(const float* __restrict__ f0, const float* __restrict__ f1,
                        const float* __restrict__ f2, const float* __restrict__ f3,
                        float* __restrict__ TM, float* __restrict__ AM){
  int f = blockIdx.x, b = blockIdx.y;
  const float* src = (f==0)? f0 : (f==1)? f1 : (f==2)? f2 : f3;
  __shared__ unsigned int flags[33];
  if (threadIdx.x < 33) flags[threadIdx.x] = 0u;
  __syncthreads();
  for (int t = 0; t < 32; t++){
    const float* row = src + ((size_t)b*NLF + t)*NE;
    bool nz = false;
    for (int d = threadIdx.x; d < NE; d += 256) nz |= (row[d] != 0.f);
    if (nz) atomicOr(&flags[t], 1u);
  }
  __syncthreads();
  int side = f >> 1, fi = f & 1;
  if (threadIdx.x < 32){
    unsigned int fl = flags[threadIdx.x];
    TM[side*1024 + b*64 + fi*32 + threadIdx.x] = fl ? 1.f : 0.f;
    if (fl) atomicOr(&flags[32], 1u);
  }
  __syncthreads();
  if (threadIdx.x == 0) AM[side*32 + b*2 + fi] = flags[32] ? 1.f : 0.f;
}

// ---------------- convert all 6 Whh chains to bf16 (layout [chain][g][k]) ----------------
__global__ void k_prep_whh(const float* __restrict__ w0, const float* __restrict__ w12,
                           unsigned short* __restrict__ dst){
  int idx = blockIdx.x*256 + threadIdx.x;   // < 1179648
  float v = (idx < 393216) ? w0[idx] : w12[idx - 393216];
  dst[idx] = f2bf_(v);
}

// ---------------- generic NT GEMM: C[z] = A @ W[z]^T + bias[z]; tile 128x128, 8x8/thread ----------------
__global__ __launch_bounds__(256) void k_gemm_nt(
    const float* __restrict__ A,
    const float* __restrict__ Wb, long wsz,
    const float* __restrict__ biasb, long bsz,
    float* __restrict__ Cb, long csz,
    int M, int N, int K)
{
  int z = blockIdx.z;
  const float* W = Wb + (size_t)z*wsz;
  const float* bias = biasb + (size_t)z*bsz;
  float* C = Cb + (size_t)z*csz;
  int n0 = blockIdx.x*128, m0 = blockIdx.y*128;
  __shared__ float As[16][132];
  __shared__ float Ws[16][132];
  int tid = threadIdx.x;
  int tm = tid >> 4, tn = tid & 15;
  int lk = tid & 15, lr = tid >> 4;
  float acc[8][8];
  #pragma unroll
  for (int r = 0; r < 8; r++)
    #pragma unroll
    for (int c = 0; c < 8; c++) acc[r][c] = 0.f;

  for (int k0 = 0; k0 < K; k0 += 16){
    #pragma unroll
    for (int i = 0; i < 8; i++)
      As[lk][lr + 16*i] = A[(size_t)(m0 + lr + 16*i)*K + k0 + lk];
    #pragma unroll
    for (int i = 0; i < 8; i++)
      Ws[lk][lr + 16*i] = W[(size_t)(n0 + lr + 16*i)*K + k0 + lk];
    __syncthreads();
    #pragma unroll 4
    for (int kk = 0; kk < 16; kk++){
      float4 a0 = *(const float4*)&As[kk][tm*8];
      float4 a1 = *(const float4*)&As[kk][tm*8+4];
      float4 w0 = *(const float4*)&Ws[kk][tn*8];
      float4 w1 = *(const float4*)&Ws[kk][tn*8+4];
      float av[8] = {a0.x,a0.y,a0.z,a0.w,a1.x,a1.y,a1.z,a1.w};
      float wv[8] = {w0.x,w0.y,w0.z,w0.w,w1.x,w1.y,w1.z,w1.w};
      #pragma unroll
      for (int r = 0; r < 8; r++)
        #pragma unroll
        for (int c = 0; c < 8; c++)
          acc[r][c] = fmaf(av[r], wv[c], acc[r][c]);
    }
    __syncthreads();
  }
  #pragma unroll
  for (int r = 0; r < 8; r++){
    size_t crow = (size_t)(m0 + tm*8 + r)*N;
    #pragma unroll
    for (int c = 0; c < 8; c++){
      int n = n0 + tn*8 + c;
      C[crow + n] = acc[r][c] + bias[n];
    }
  }
}

// ---------------- GRU scan: one block per (dir, pair of b'), h in LDS, bf16 Whh ----------------
__global__ __launch_bounds__(512) void k_scan(
    const float* __restrict__ xi,            // [2][2048][768]
    const unsigned short* __restrict__ whh,  // [6][768][256] bf16
    const float* __restrict__ bhhb, long bhh_stride,
    float* __restrict__ Hout,                // [2048][512]
    int chain0)
{
  int dir = blockIdx.y;
  int bp  = blockIdx.x;
  int tid = threadIdx.x;
  int bloc = tid >> 8;
  int u = tid & 255;
  int bprime = bp*2 + bloc;
  const unsigned short* W = whh + (size_t)(chain0 + dir)*NG3*NH;
  const float* bhh = bhhb + (size_t)dir*bhh_stride;
  const float* xid = xi + (size_t)dir*NBT*NG3;
  __shared__ float hl[2][256];
  hl[bloc][u] = 0.f;
  __syncthreads();
  const uint4* w0p = (const uint4*)(W + (size_t)u*NH);
  const uint4* w1p = (const uint4*)(W + (size_t)(256+u)*NH);
  const uint4* w2p = (const uint4*)(W + (size_t)(512+u)*NH);
  float b0 = bhh[u], b1 = bhh[256+u], b2 = bhh[512+u];
  for (int s = 0; s < 32; s++){
    int t = dir ? (31 - s) : s;
    float a0 = b0, a1 = b1, a2 = b2;
    #pragma unroll 4
    for (int kc = 0; kc < 32; kc++){
      uint4 wa = w0p[kc], wb = w1p[kc], wc = w2p[kc];
      float4 h0 = *(const float4*)&hl[bloc][kc*8];
      float4 h1 = *(const float4*)&hl[bloc][kc*8+4];
      a0 = fmaf(h0.x, bflo_(wa.x), a0); a0 = fmaf(h0.y, bfhi_(wa.x), a0);
      a0 = fmaf(h0.z, bflo_(wa.y), a0); a0 = fmaf(h0.w, bfhi_(wa.y), a0);
      a0 = fmaf(h1.x, bflo_(wa.z), a0); a0 = fmaf(h1.y, bfhi_(wa.z), a0);
      a0 = fmaf(h1.z, bflo_(wa.w), a0); a0 = fmaf(h1.w, bfhi_(wa.w), a0);
      a1 = fmaf(h0.x, bflo_(wb.x), a1); a1 = fmaf(h0.y, bfhi_(wb.x), a1);
      a1 = fmaf(h0.z, bflo_(wb.y), a1); a1 = fmaf(h0.w, bfhi_(wb.y), a1);
      a1 = fmaf(h1.x, bflo_(wb.z), a1); a1 = fmaf(h1.y, bfhi_(wb.z), a1);
      a1 = fmaf(h1.z, bflo_(wb.w), a1); a1 = fmaf(h1.w, bfhi_(wb.w), a1);
      a2 = fmaf(h0.x, bflo_(wc.x), a2); a2 = fmaf(h0.y, bfhi_(wc.x), a2);
      a2 = fmaf(h0.z, bflo_(wc.y), a2); a2 = fmaf(h0.w, bfhi_(wc.y), a2);
      a2 = fmaf(h1.x, bflo_(wc.z), a2); a2 = fmaf(h1.y, bfhi_(wc.z), a2);
      a2 = fmaf(h1.z, bflo_(wc.w), a2); a2 = fmaf(h1.w, bfhi_(wc.w), a2);
    }
    size_t m = (size_t)bprime*NLF + t;
    const float* xr = xid + m*NG3;
    float ir = xr[u], iz = xr[256+u], inn = xr[512+u];
    float r  = sigmoidf_(ir + a0);
    float zz = sigmoidf_(iz + a1);
    float nn = tanhf(inn + r*a2);
    float hprev = hl[bloc][u];
    float hnew = (1.f - zz)*nn + zz*hprev;
    __syncthreads();
    hl[bloc][u] = hnew;
    Hout[m*NH2 + dir*256 + u] = hnew;
    __syncthreads();
  }
}

// ---------------- token-matching scores S[b][i][j] (fused highway + lint dot) ----------------
__global__ __launch_bounds__(256) void k_token_scores(
    const float* __restrict__ Hf,
    const float* __restrict__ Wn, const float* __restrict__ Wg,
    const float* __restrict__ bn, const float* __restrict__ bg,
    const float* __restrict__ lintW, const float* __restrict__ lintB,
    float* __restrict__ S)
{
  __shared__ float Ls[2][512];
  __shared__ float cms[32][132];
  __shared__ float Wns[32][68];
  __shared__ float Wgs[32][68];
  __shared__ float bns[512], bgs[512], lws[512];
  __shared__ float sred[128][17];
  int ip = blockIdx.x, b = blockIdx.y;
  int tid = threadIdx.x;
  int r0 = tokrow(0, b, ip*2);
  int r1 = tokrow(0, b, ip*2+1);
  for (int d = tid; d < 512; d += 256){
    Ls[0][d] = Hf[(size_t)r0*NH2 + d];
    Ls[1][d] = Hf[(size_t)r1*NH2 + d];
    bns[d] = bn[d]; bgs[d] = bg[d]; lws[d] = lintW[d];
  }
  __syncthreads();
  int tm = tid >> 4, tn = tid & 15;
  int sj = tid >> 2, skq = tid & 3;
  const float* Rst = Hf + (size_t)tokrow(1, b, sj)*NH2;
  float score[8];
  #pragma unroll
  for (int rr = 0; rr < 8; rr++) score[rr] = 0.f;

  for (int nc = 0; nc < 8; nc++){
    int n0 = nc*64;
    float accn[8][4], accg[8][4];
    #pragma unroll
    for (int rr = 0; rr < 8; rr++)
      #pragma unroll
      for (int nn = 0; nn < 4; nn++){ accn[rr][nn] = 0.f; accg[rr][nn] = 0.f; }

    for (int kc = 0; kc < 16; kc++){
      int k0 = kc*32;
      float4 ra = *(const float4*)&Rst[k0 + skq*8];
      float4 rb = *(const float4*)&Rst[k0 + skq*8 + 4];
      float rv[8] = {ra.x,ra.y,ra.z,ra.w,rb.x,rb.y,rb.z,rb.w};
      #pragma unroll
      for (int q = 0; q < 8; q++){
        int kk = skq*8 + q;
        cms[kk][sj]      = fabsf(Ls[0][k0+kk] - rv[q]);
        cms[kk][64 + sj] = fabsf(Ls[1][k0+kk] - rv[q]);
      }
      const float* wnr = Wn + (size_t)(n0 + sj)*512 + k0 + skq*8;
      const float* wgr = Wg + (size_t)(n0 + sj)*512 + k0 + skq*8;
      float4 wa = *(const float4*)wnr; float4 wbv = *(const float4*)(wnr+4);
      float4 ga = *(const float4*)wgr; float4 gb = *(const float4*)(wgr+4);
      float wv[8] = {wa.x,wa.y,wa.z,wa.w,wbv.x,wbv.y,wbv.z,wbv.w};
      float gv[8] = {ga.x,ga.y,ga.z,ga.w,gb.x,gb.y,gb.z,gb.w};
      #pragma unroll
      for (int q = 0; q < 8; q++){
        int kk = skq*8 + q;
        Wns[kk][sj] = wv[q];
        Wgs[kk][sj] = gv[q];
      }
      __syncthreads();
      #pragma unroll 4
      for (int kk = 0; kk < 32; kk++){
        float4 c0 = *(const float4*)&cms[kk][tm*8];
        float4 c1 = *(const float4*)&cms[kk][tm*8+4];
        float4 w4 = *(const float4*)&Wns[kk][tn*4];
        float4 g4 = *(const float4*)&Wgs[kk][tn*4];
        float cv[8] = {c0.x,c0.y,c0.z,c0.w,c1.x,c1.y,c1.z,c1.w};
        float wn4[4] = {w4.x,w4.y,w4.z,w4.w};
        float gg4[4] = {g4.x,g4.y,g4.z,g4.w};
        #pragma unroll
        for (int rr = 0; rr < 8; rr++)
          #pragma unroll
          for (int nn = 0; nn < 4; nn++){
            accn[rr][nn] = fmaf(cv[rr], wn4[nn], accn[rr][nn]);
            accg[rr][nn] = fmaf(cv[rr], gg4[nn], accg[rr][nn]);
          }
      }
      __syncthreads();
    }
    #pragma unroll
    for (int rr = 0; rr < 8; rr++){
      int r = tm*8 + rr;
      int isel = r >> 6, j = r & 63;
      const float* Rr = Hf + (size_t)tokrow(1, b, j)*NH2;
      #pragma unroll
      for (int nn = 0; nn < 4; nn++){
        int n = n0 + tn*4 + nn;
        float an = accn[rr][nn] + bns[n];
        float ag = accg[rr][nn] + bgs[n];
        float g = sigmoidf_(ag);
        float cmv = fabsf(Ls[isel][n] - Rr[n]);
        float hwv = fmaxf(an, 0.f)*g + (1.f - g)*cmv;
        score[rr] = fmaf(lws[n], hwv, score[rr]);
      }
    }
  }
  #pragma unroll
  for (int rr = 0; rr < 8; rr++) sred[tm*8+rr][tn] = score[rr];
  __syncthreads();
  if (tid < 128){
    float s = 0.f;
    #pragma unroll
    for (int q = 0; q < 16; q++) s += sred[tid][q];
    s += lintB[0];
    int isel = tid >> 6, j = tid & 63;
    int i = ip*2 + isel;
    S[((size_t)b*64 + i)*64 + j] = s;
  }
}

// ---------------- softmaxes over j (w_l) and over i (w_r) ----------------
__global__ void k_softmax_wl(const float* __restrict__ S, const float* __restrict__ TM,
                             float* __restrict__ WLo){
  int i = blockIdx.x, b = blockIdx.y, j = threadIdx.x;
  float mask = TM[1024 + b*64 + j];
  float v = S[((size_t)b*64 + i)*64 + j] + (mask != 0.f ? 0.f : -1e10f);
  float m = v;
  for (int o = 32; o; o >>= 1) m = fmaxf(m, __shfl_xor(m, o));
  float e = expf(v - m), s = e;
  for (int o = 32; o; o >>= 1) s += __shfl_xor(s, o);
  WLo[((size_t)b*64 + i)*64 + j] = e / s;
}
__global__ void k_softmax_wr(const float* __restrict__ S, const float* __restrict__ TM,
                             float* __restrict__ WRo){
  int j = blockIdx.x, b = blockIdx.y, i = threadIdx.x;
  float mask = TM[b*64 + i];
  float v = S[((size_t)b*64 + i)*64 + j] + (mask != 0.f ? 0.f : -1e10f);
  float m = v;
  for (int o = 32; o; o >>= 1) m = fmaxf(m, __shfl_xor(m, o));
  float e = expf(v - m), s = e;
  for (int o = 32; o; o >>= 1) s += __shfl_xor(s, o);
  WRo[((size_t)b*64 + j)*64 + i] = e / s;
}

// ---------------- weighted |L-R| sums: out[b][p][:] = sum_q w[b][p][q]*|X[p]-Y[q]| ----------------
__global__ __launch_bounds__(256) void k_cmp(const float* __restrict__ Hf,
    const float* __restrict__ w, float* __restrict__ out, int side){
  int p = blockIdx.x, b = blockIdx.y;
  __shared__ float wl[64];
  if (threadIdx.x < 64) wl[threadIdx.x] = w[((size_t)b*64 + p)*64 + threadIdx.x];
  __syncthreads();
  int xr = tokrow(side, b, p);
  int d1 = threadIdx.x, d2 = threadIdx.x + 256;
  float x1 = Hf[(size_t)xr*NH2 + d1], x2 = Hf[(size_t)xr*NH2 + d2];
  float a1 = 0.f, a2 = 0.f;
  for (int q = 0; q < 64; q++){
    const float* yr = Hf + (size_t)tokrow(side^1, b, q)*NH2;
    float wq = wl[q];
    a1 += wq * fabsf(x1 - yr[d1]);
    a2 += wq * fabsf(x2 - yr[d2]);
  }
  out[((size_t)b*64 + p)*NH2 + d1] = a1;
  out[((size_t)b*64 + p)*NH2 + d2] = a2;
}

// ---------------- attribute matching -> concat buffer ----------------
__global__ __launch_bounds__(256) void k_attr(const float* __restrict__ Hf,
    const float* __restrict__ attrL, const float* __restrict__ attrR,
    const float* __restrict__ LC, const float* __restrict__ RC,
    const float* __restrict__ TM, const float* __restrict__ AM,
    const float* __restrict__ emptyA, float* __restrict__ CC){
  int fi = blockIdx.x, b = blockIdx.y, side = blockIdx.z;
  const float* attr = (side ? attrR : attrL) + fi*512;
  const float* cmp = side ? RC : LC;
  __shared__ float sc[32], wv[32];
  int t = threadIdx.x >> 3, l8 = threadIdx.x & 7;
  const float* er = Hf + (size_t)tokrow(side, b, fi*32 + t)*NH2;
  float acc = 0.f;
  for (int d = l8*64; d < l8*64 + 64; d++) acc += er[d]*attr[d];
  acc += __shfl_down(acc, 4, 8);
  acc += __shfl_down(acc, 2, 8);
  acc += __shfl_down(acc, 1, 8);
  if (l8 == 0) sc[t] = acc;
  __syncthreads();
  if (threadIdx.x < 32){
    float mask = TM[side*1024 + b*64 + fi*32 + threadIdx.x];
    float v = sc[threadIdx.x] + (mask != 0.f ? 0.f : -1e10f);
    float m = v;
    for (int o = 16; o; o >>= 1) m = fmaxf(m, __shfl_xor(m, o, 32));
    float e = expf(v - m), s = e;
    for (int o = 16; o; o >>= 1) s += __shfl_xor(s, o, 32);
    wv[threadIdx.x] = e / s;
  }
  __syncthreads();
  float am = AM[side*32 + b*2 + fi];
  int d1 = threadIdx.x, d2 = threadIdx.x + 256;
  float a1 = 0.f, a2 = 0.f;
  for (int t2 = 0; t2 < 32; t2++){
    float wq = wv[t2];
    const float* cr = cmp + ((size_t)b*64 + fi*32 + t2)*NH2;
    a1 += wq * cr[d1];
    a2 += wq * cr[d2];
  }
  float* dst = CC + (size_t)b*NDE + (size_t)(side*2 + fi)*512;
  dst[d1] = (am != 0.f) ? a1 : emptyA[d1];
  dst[d2] = (am != 0.f) ? a2 : emptyA[d2];
}

// ---------------- final highway (2048x2048) ----------------
__global__ __launch_bounds__(256) void k_final_hw(const float* __restrict__ X,
    const float* __restrict__ Wn, const float* __restrict__ bn,
    const float* __restrict__ Wg, const float* __restrict__ bg,
    float* __restrict__ HWo){
  __shared__ float Xs[4][2048];
  int nb = blockIdx.x, bq = blockIdx.y;
  for (int idx = threadIdx.x; idx < 8192; idx += 256)
    Xs[idx>>11][idx & 2047] = X[(size_t)(bq*4 + (idx>>11))*NDE + (idx & 2047)];
  __syncthreads();
  int nl = threadIdx.x >> 1, kl = threadIdx.x & 1;
  int n = nb*128 + nl;
  const float* wnr = Wn + (size_t)n*NDE + kl*1024;
  const float* wgr = Wg + (size_t)n*NDE + kl*1024;
  float an[4] = {0,0,0,0}, ag[4] = {0,0,0,0};
  for (int k = 0; k < 1024; k++){
    float wn = wnr[k], wg = wgr[k];
    int kk = kl*1024 + k;
    #pragma unroll
    for (int b4 = 0; b4 < 4; b4++){
      float xv = Xs[b4][kk];
      an[b4] = fmaf(wn, xv, an[b4]);
      ag[b4] = fmaf(wg, xv, ag[b4]);
    }
  }
  #pragma unroll
  for (int b4 = 0; b4 < 4; b4++){
    an[b4] += __shfl_down(an[b4], 1);
    ag[b4] += __shfl_down(ag[b4], 1);
  }
  if (kl == 0){
    float bnv = bn[n], bgv = bg[n];
    #pragma unroll
    for (int b4 = 0; b4 < 4; b4++){
      float a = an[b4] + bnv;
      float g = sigmoidf_(ag[b4] + bgv);
      float xv = Xs[b4][n];
      HWo[(size_t)(bq*4 + b4)*NDE + n] = fmaxf(a, 0.f)*g + (1.f - g)*xv;
    }
  }
}

// ---------------- linear + log_softmax ----------------
__global__ void k_out(const float* __restrict__ HWi, const float* __restrict__ lw,
                      const float* __restrict__ lb, float* __restrict__ out){
  int b = blockIdx.x, lane = threadIdx.x;
  float p0 = 0.f, p1 = 0.f;
  for (int n = lane; n < 2048; n += 64){
    float h = HWi[(size_t)b*NDE + n];
    p0 += h * lw[n];
    p1 += h * lw[2048 + n];
  }
  for (int o = 32; o; o >>= 1){ p0 += __shfl_xor(p0, o); p1 += __shfl_xor(p1, o); }
  if (lane == 0){
    float o0 = p0 + lb[0], o1 = p1 + lb[1];
    float m = fmaxf(o0, o1);
    float lse = m + logf(expf(o0 - m) + expf(o1 - m));
    out[b*2]   = o0 - lse;
    out[b*2+1] = o1 - lse;
  }
}

extern "C" void kernel_launch(void* const* d_in, const int* in_sizes, int n_in,
                              void* d_out, int out_size, void* d_ws, size_t ws_size,
                              hipStream_t stream){
  const float* lf0 = (const float*)d_in[0];
  const float* lf1 = (const float*)d_in[1];
  const float* rf0 = (const float*)d_in[2];
  const float* rf1 = (const float*)d_in[3];
  const float* gWih0 = (const float*)d_in[4];
  const float* gWhh0 = (const float*)d_in[5];
  const float* gbih0 = (const float*)d_in[6];
  const float* gbhh0 = (const float*)d_in[7];
  const float* gWih12 = (const float*)d_in[8];
  const float* gWhh12 = (const float*)d_in[9];
  const float* gbih12 = (const float*)d_in[10];
  const float* gbhh12 = (const float*)d_in[11];
  const float* hwtWn = (const float*)d_in[12];
  const float* hwtbn = (const float*)d_in[13];
  const float* hwtWg = (const float*)d_in[14];
  const float* hwtbg = (const float*)d_in[15];
  const float* lintW = (const float*)d_in[16];
  const float* lintB = (const float*)d_in[17];
  const float* attrL = (const float*)d_in[18];
  const float* attrR = (const float*)d_in[19];
  const float* emptyA = (const float*)d_in[20];
  const float* hweWn = (const float*)d_in[21];
  const float* hwebn = (const float*)d_in[22];
  const float* hweWg = (const float*)d_in[23];
  const float* hwebg = (const float*)d_in[24];
  const float* lineW = (const float*)d_in[25];
  const float* lineB = (const float*)d_in[26];
  float* out = (float*)d_out;

  // workspace layout (floats); total ~8.7M floats (~35 MB)
  float* ws = (float*)d_ws;
  float* X0   = ws;                         // 2048*768
  float* XI   = X0 + (size_t)NBT*NE;        // 2*2048*768
  float* HA   = XI + (size_t)2*NBT*NG3;     // 2048*512
  float* HB   = HA + (size_t)NBT*NH2;       // 2048*512
  unsigned short* WHH = (unsigned short*)(HB + (size_t)NBT*NH2); // 6*768*256 bf16
  float* Sb   = (float*)(WHH + (size_t)6*NG3*NH);
  float* WLb  = Sb  + 16*64*64;
  float* WRb  = WLb + 16*64*64;
  float* LC   = WRb + 16*64*64;
  float* RC   = LC + (size_t)16*64*512;
  float* TM   = RC + (size_t)16*64*512;
  float* AM   = TM + 2*16*64;
  float* CC   = AM + 64;
  float* HWb  = CC + 16*2048;

  k_gather<<<NBT, 256, 0, stream>>>(lf0, lf1, rf0, rf1, X0);
  k_masks<<<dim3(4,16), 256, 0, stream>>>(lf0, lf1, rf0, rf1, TM, AM);
  k_prep_whh<<<4608, 256, 0, stream>>>(gWhh0, gWhh12, WHH);

  // layer 0
  k_gemm_nt<<<dim3(6,16,2), 256, 0, stream>>>(X0, gWih0, (long)NG3*NE, gbih0, NG3,
                                              XI, (long)NBT*NG3, NBT, NG3, NE);
  k_scan<<<dim3(32,2), 512, 0, stream>>>(XI, WHH, gbhh0, NG3, HA, 0);
  // layer 1
  k_gemm_nt<<<dim3(6,16,2), 256, 0, stream>>>(HA, gWih12, (long)NG3*NH2, gbih12, NG3,
                                              XI, (long)NBT*NG3, NBT, NG3, NH2);
  k_scan<<<dim3(32,2), 512, 0, stream>>>(XI, WHH, gbhh12, NG3, HB, 2);
  // layer 2
  k_gemm_nt<<<dim3(6,16,2), 256, 0, stream>>>(HB, gWih12 + (size_t)2*NG3*NH2, (long)NG3*NH2,
                                              gbih12 + 2*NG3, NG3,
                                              XI, (long)NBT*NG3, NBT, NG3, NH2);
  k_scan<<<dim3(32,2), 512, 0, stream>>>(XI, WHH, gbhh12 + 2*NG3, NG3, HA, 4);

  // token matching
  k_token_scores<<<dim3(32,16), 256, 0, stream>>>(HA, hwtWn, hwtWg, hwtbn, hwtbg,
                                                  lintW, lintB, Sb);
  k_softmax_wl<<<dim3(64,16), 64, 0, stream>>>(Sb, TM, WLb);
  k_softmax_wr<<<dim3(64,16), 64, 0, stream>>>(Sb, TM, WRb);
  k_cmp<<<dim3(64,16), 256, 0, stream>>>(HA, WLb, LC, 0);
  k_cmp<<<dim3(64,16), 256, 0, stream>>>(HA, WRb, RC, 1);

  // attribute matching -> concat
  k_attr<<<dim3(2,16,2), 256, 0, stream>>>(HA, attrL, attrR, LC, RC, TM, AM, emptyA, CC);

  // final highway + classifier
  k_final_hw<<<dim3(16,4), 256, 0, stream>>>(CC, hweWn, hwebn, hweWg, hwebg, HWb);
  k_out<<<16, 64, 0, stream>>>(HWb, lineW, lineB, out);
}

// Round 2
// 1749.496 us; speedup vs baseline: 2.1478x; 2.1478x over previous
//
#include <hip/hip_runtime.h>
#include <hip/hip_bf16.h>

#define NH 256      // H
#define NE 768      // E
#define NH2 512
#define NG3 768     // 3*H
#define NB 16
#define NLF 32
#define NBT 2048    // 4 fields * 16 * 32 rows
#define NDE 2048

typedef short s16x8 __attribute__((ext_vector_type(8)));
typedef float f32x4 __attribute__((ext_vector_type(4)));

// swizzle: granule g (8 bf16) of row r stored at position (g + (r>>1)) & 3
#define TK_SWZ(g, r) (((g) + ((r) >> 1)) & 3)

__device__ __forceinline__ float sigmoidf_(float x){ return 1.f/(1.f+expf(-x)); }
__device__ __forceinline__ float bflo_(unsigned int x){ return __uint_as_float(x<<16); }
__device__ __forceinline__ float bfhi_(unsigned int x){ return __uint_as_float(x & 0xffff0000u); }
__device__ __forceinline__ unsigned short f2bf_(float f){
  unsigned int x = __float_as_uint(f);
  unsigned int r = (x + 0x7fffu + ((x>>16)&1u)) >> 16;
  return (unsigned short)r;
}
// pack 2 floats to 2 bf16 (round-half-up) in one u32: low=a, high=b
__device__ __forceinline__ unsigned int pack_bf16_rnd(float a, float b){
  unsigned int ua = __float_as_uint(a) + 0x8000u;
  unsigned int ub = __float_as_uint(b) + 0x8000u;
  return __builtin_amdgcn_perm(ub, ua, 0x07060302u);
}
// row in the (2048 x 512) embedding buffer for (side, b, tok)
__device__ __forceinline__ int tokrow(int side, int b, int tok){
  return (((side*2 + (tok>>5))*16 + b) << 5) + (tok & 31);
}

// ---------------- gather 4 fields into X0 (2048 x 768) ----------------
__global__ void k_gather(const float* __restrict__ f0, const float* __restrict__ f1,
                         const float* __restrict__ f2, const float* __restrict__ f3,
                         float* __restrict__ X0){
  int m = blockIdx.x;
  int f = m >> 9, rem = m & 511;
  const float* src = (f==0)? f0 : (f==1)? f1 : (f==2)? f2 : f3;
  const float* sp = src + (size_t)rem*NE;
  float* dp = X0 + (size_t)m*NE;
  for (int d = threadIdx.x; d < NE; d += 256) dp[d] = sp[d];
}

// ---------------- token & attribute masks ----------------
__global__ void k_masks(const float* __restrict__ f0, const float* __restrict__ f1,
                        const float* __restrict__ f2, const float* __restrict__ f3,
                        float* __restrict__ TM, float* __restrict__ AM){
  int f = blockIdx.x, b = blockIdx.y;
  const float* src = (f==0)? f0 : (f==1)? f1 : (f==2)? f2 : f3;
  __shared__ unsigned int flags[33];
  if (threadIdx.x < 33) flags[threadIdx.x] = 0u;
  __syncthreads();
  for (int t = 0; t < 32; t++){
    const float* row = src + ((size_t)b*NLF + t)*NE;
    bool nz = false;
    for (int d = threadIdx.x; d < NE; d += 256) nz |= (row[d] != 0.f);
    if (nz) atomicOr(&flags[t], 1u);
  }
  __syncthreads();
  int side = f >> 1, fi = f & 1;
  if (threadIdx.x < 32){
    unsigned int fl = flags[threadIdx.x];
    TM[side*1024 + b*64 + fi*32 + threadIdx.x] = fl ? 1.f : 0.f;
    if (fl) atomicOr(&flags[32], 1u);
  }
  __syncthreads();
  if (threadIdx.x == 0) AM[side*32 + b*2 + fi] = flags[32] ? 1.f : 0.f;
}

// ---------------- convert all 6 Whh chains to bf16 ----------------
__global__ void k_prep_whh(const float* __restrict__ w0, const float* __restrict__ w12,
                           unsigned short* __restrict__ dst){
  int idx = blockIdx.x*256 + threadIdx.x;   // < 1179648
  float v = (idx < 393216) ? w0[idx] : w12[idx - 393216];
  dst[idx] = f2bf_(v);
}

// ---------------- prep token weights: TW[nc][kc][n(interleaved)][k32] bf16, pre-swizzled ----------------
__global__ void k_prep_tw(const float* __restrict__ Wn, const float* __restrict__ Wg,
                          unsigned short* __restrict__ TW){
  int idx = blockIdx.x*256 + threadIdx.x;   // < 524288
  int kpos = idx & 31;
  int n    = (idx >> 5) & 127;
  int kc   = (idx >> 12) & 15;
  int nc   = idx >> 16;
  int gpos = kpos >> 3, j = kpos & 7;
  int gorig = (gpos - (n>>1)) & 3;
  int k = kc*32 + gorig*8 + j;
  int q = n >> 1, type = n & 1;
  const float* src = type ? Wg : Wn;
  TW[idx] = f2bf_(src[(size_t)(nc*64 + q)*NH2 + k]);
}

// ---------------- bf16 MFMA NT GEMM: C[z] = A @ W[z]^T + bias[z]; 128x128 tile ----------------
__global__ __launch_bounds__(256) void k_gemm_mfma(
    const float* __restrict__ A,
    const float* __restrict__ Wb, long wsz,
    const float* __restrict__ biasb, long bsz,
    float* __restrict__ Cb, long csz,
    int M, int N, int K)
{
  int z = blockIdx.z;
  const float* W = Wb + (size_t)z*wsz;
  const float* bias = biasb + (size_t)z*bsz;
  float* C = Cb + (size_t)z*csz;
  int n0 = blockIdx.x*128, m0 = blockIdx.y*128;
  __shared__ short At[128*32];
  __shared__ short Wt[128*32];
  int tid = threadIdx.x;
  int wave = tid >> 6, wm = wave >> 1, wn = wave & 1;
  int lane = tid & 63, l15 = lane & 15, lq = lane >> 4;
  int sm = tid & 127, gb = (tid >> 7) * 2;

  f32x4 zero4 = {0.f,0.f,0.f,0.f};
  f32x4 acc[4][4];
  #pragma unroll
  for (int mi=0;mi<4;mi++)
    #pragma unroll
    for (int nj=0;nj<4;nj++) acc[mi][nj] = zero4;

  const float* ar = A + (size_t)(m0 + sm)*K;
  const float* wr = W + (size_t)(n0 + sm)*K;

  for (int k0 = 0; k0 < K; k0 += 32){
    #pragma unroll
    for (int gi = 0; gi < 2; gi++){
      int g = gb + gi;
      const float* ap = ar + k0 + g*8;
      float4 a0 = *(const float4*)ap, a1 = *(const float4*)(ap+4);
      uint4 pa = { pack_bf16_rnd(a0.x,a0.y), pack_bf16_rnd(a0.z,a0.w),
                   pack_bf16_rnd(a1.x,a1.y), pack_bf16_rnd(a1.z,a1.w) };
      *(uint4*)&At[sm*32 + TK_SWZ(g,sm)*8] = pa;
      const float* wp = wr + k0 + g*8;
      float4 w0 = *(const float4*)wp, w1 = *(const float4*)(wp+4);
      uint4 pw = { pack_bf16_rnd(w0.x,w0.y), pack_bf16_rnd(w0.z,w0.w),
                   pack_bf16_rnd(w1.x,w1.y), pack_bf16_rnd(w1.z,w1.w) };
      *(uint4*)&Wt[sm*32 + TK_SWZ(g,sm)*8] = pw;
    }
    __syncthreads();
    s16x8 af[4], wf[4];
    #pragma unroll
    for (int mi=0;mi<4;mi++){
      int row = wm*64 + mi*16 + l15;
      af[mi] = *(const s16x8*)&At[row*32 + TK_SWZ(lq,row)*8];
    }
    #pragma unroll
    for (int nj=0;nj<4;nj++){
      int row = wn*64 + nj*16 + l15;
      wf[nj] = *(const s16x8*)&Wt[row*32 + TK_SWZ(lq,row)*8];
    }
    #pragma unroll
    for (int mi=0;mi<4;mi++)
      #pragma unroll
      for (int nj=0;nj<4;nj++)
        acc[mi][nj] = __builtin_amdgcn_mfma_f32_16x16x32_bf16(af[mi], wf[nj], acc[mi][nj], 0,0,0);
    __syncthreads();
  }
  // epilogue: C[m][n] = acc + bias[n]; D layout: n = l&15, m = lq*4 + reg
  #pragma unroll
  for (int nj=0;nj<4;nj++){
    int n = n0 + wn*64 + nj*16 + l15;
    float bv = bias[n];
    #pragma unroll
    for (int mi=0;mi<4;mi++){
      int mbase = m0 + wm*64 + mi*16 + lq*4;
      #pragma unroll
      for (int r=0;r<4;r++)
        C[(size_t)(mbase + r)*N + n] = acc[mi][nj][r] + bv;
    }
  }
}

// ---------------- GRU scan: one block per (dir, b'), h in LDS, bf16 Whh ----------------
__global__ __launch_bounds__(256) void k_scan(
    const float* __restrict__ xi,            // [2][2048][768]
    const unsigned short* __restrict__ whh,  // [6][768][256] bf16
    const float* __restrict__ bhhb, long bhh_stride,
    float* __restrict__ Hout,                // [2048][512]
    int chain0)
{
  int dir = blockIdx.y;
  int bprime = blockIdx.x;
  int u = threadIdx.x;
  const unsigned short* W = whh + (size_t)(chain0 + dir)*NG3*NH;
  const float* bhh = bhhb + (size_t)dir*bhh_stride;
  const float* xid = xi + (size_t)dir*NBT*NG3;
  __shared__ float hl[256];
  hl[u] = 0.f;
  __syncthreads();
  const uint4* w0p = (const uint4*)(W + (size_t)u*NH);
  const uint4* w1p = (const uint4*)(W + (size_t)(256+u)*NH);
  const uint4* w2p = (const uint4*)(W + (size_t)(512+u)*NH);
  float b0 = bhh[u], b1 = bhh[256+u], b2 = bhh[512+u];
  for (int s = 0; s < 32; s++){
    int t = dir ? (31 - s) : s;
    float a0 = b0, a1 = b1, a2 = b2;
    #pragma unroll 4
    for (int kc = 0; kc < 32; kc++){
      uint4 wa = w0p[kc], wb = w1p[kc], wc = w2p[kc];
      float4 h0 = *(const float4*)&hl[kc*8];
      float4 h1 = *(const float4*)&hl[kc*8+4];
      a0 = fmaf(h0.x, bflo_(wa.x), a0); a0 = fmaf(h0.y, bfhi_(wa.x), a0);
      a0 = fmaf(h0.z, bflo_(wa.y), a0); a0 = fmaf(h0.w, bfhi_(wa.y), a0);
      a0 = fmaf(h1.x, bflo_(wa.z), a0); a0 = fmaf(h1.y, bfhi_(wa.z), a0);
      a0 = fmaf(h1.z, bflo_(wa.w), a0); a0 = fmaf(h1.w, bfhi_(wa.w), a0);
      a1 = fmaf(h0.x, bflo_(wb.x), a1); a1 = fmaf(h0.y, bfhi_(wb.x), a1);
      a1 = fmaf(h0.z, bflo_(wb.y), a1); a1 = fmaf(h0.w, bfhi_(wb.y), a1);
      a1 = fmaf(h1.x, bflo_(wb.z), a1); a1 = fmaf(h1.y, bfhi_(wb.z), a1);
      a1 = fmaf(h1.z, bflo_(wb.w), a1); a1 = fmaf(h1.w, bfhi_(wb.w), a1);
      a2 = fmaf(h0.x, bflo_(wc.x), a2); a2 = fmaf(h0.y, bfhi_(wc.x), a2);
      a2 = fmaf(h0.z, bflo_(wc.y), a2); a2 = fmaf(h0.w, bfhi_(wc.y), a2);
      a2 = fmaf(h1.x, bflo_(wc.z), a2); a2 = fmaf(h1.y, bfhi_(wc.z), a2);
      a2 = fmaf(h1.z, bflo_(wc.w), a2); a2 = fmaf(h1.w, bfhi_(wc.w), a2);
    }
    size_t m = (size_t)bprime*NLF + t;
    const float* xr = xid + m*NG3;
    float ir = xr[u], iz = xr[256+u], inn = xr[512+u];
    float r  = sigmoidf_(ir + a0);
    float zz = sigmoidf_(iz + a1);
    float nn = tanhf(inn + r*a2);
    float hprev = hl[u];
    float hnew = (1.f - zz)*nn + zz*hprev;
    __syncthreads();
    hl[u] = hnew;
    Hout[m*NH2 + dir*256 + u] = hnew;
    __syncthreads();
  }
}

// ---------------- token-matching scores via MFMA: partials P[nc][b][i][j] ----------------
__global__ __launch_bounds__(256) void k_token_mfma(
    const float* __restrict__ Hf,
    const unsigned short* __restrict__ TW,   // [8][16][128][32] bf16 pre-swizzled
    const float* __restrict__ bn, const float* __restrict__ bg,
    const float* __restrict__ lintW,
    float* __restrict__ P)
{
  __shared__ short Atile[128*32];
  __shared__ short Btile[128*32];
  __shared__ short Asave[2*128*32];
  __shared__ float sred[256];
  int ip = blockIdx.x, b = blockIdx.y, nc = blockIdx.z;
  int tid = threadIdx.x;
  int wave = tid >> 6, wm = wave >> 1, wn = wave & 1;
  int lane = tid & 63, l15 = lane & 15, lq = lane >> 4;
  int m = tid & 127, gb = (tid >> 7) * 2;
  int i_ = ip*2 + (m >> 6), j_ = m & 63;
  const float* Lrow = Hf + (size_t)tokrow(0, b, i_)*NH2;
  const float* Rrow = Hf + (size_t)tokrow(1, b, j_)*NH2;
  const uint4* TWu = (const uint4*)TW + ((size_t)(nc*16))*512;

  f32x4 zero4 = {0.f,0.f,0.f,0.f};
  f32x4 acc[4][4];
  #pragma unroll
  for (int mi=0;mi<4;mi++)
    #pragma unroll
    for (int nj=0;nj<4;nj++) acc[mi][nj] = zero4;

  for (int kc = 0; kc < 16; kc++){
    int k0 = kc*32;
    // build A-tile (cm = |L - R|, bf16)
    #pragma unroll
    for (int gi = 0; gi < 2; gi++){
      int g = gb + gi;
      const float* lp = Lrow + k0 + g*8;
      const float* rp = Rrow + k0 + g*8;
      float4 l0 = *(const float4*)lp, l1 = *(const float4*)(lp+4);
      float4 r0 = *(const float4*)rp, r1 = *(const float4*)(rp+4);
      uint4 pk = { pack_bf16_rnd(fabsf(l0.x-r0.x), fabsf(l0.y-r0.y)),
                   pack_bf16_rnd(fabsf(l0.z-r0.z), fabsf(l0.w-r0.w)),
                   pack_bf16_rnd(fabsf(l1.x-r1.x), fabsf(l1.y-r1.y)),
                   pack_bf16_rnd(fabsf(l1.z-r1.z), fabsf(l1.w-r1.w)) };
      int woff = m*32 + TK_SWZ(g,m)*8;
      *(uint4*)&Atile[woff] = pk;
      int cs = kc - 2*nc;
      if ((unsigned)cs < 2u) *(uint4*)&Asave[cs*4096 + woff] = pk;
    }
    // stage B-tile (straight copy; layout pre-swizzled in prep)
    {
      const uint4* src = TWu + (size_t)kc*512;
      ((uint4*)Btile)[tid*2]   = src[tid*2];
      ((uint4*)Btile)[tid*2+1] = src[tid*2+1];
    }
    __syncthreads();
    s16x8 af[4], bfv[4];
    #pragma unroll
    for (int mi=0;mi<4;mi++){
      int row = wm*64 + mi*16 + l15;
      af[mi] = *(const s16x8*)&Atile[row*32 + TK_SWZ(lq,row)*8];
    }
    #pragma unroll
    for (int nj=0;nj<4;nj++){
      int row = wn*64 + nj*16 + l15;
      bfv[nj] = *(const s16x8*)&Btile[row*32 + TK_SWZ(lq,row)*8];
    }
    #pragma unroll
    for (int mi=0;mi<4;mi++)
      #pragma unroll
      for (int nj=0;nj<4;nj++)
        acc[mi][nj] = __builtin_amdgcn_mfma_f32_16x16x32_bf16(af[mi], bfv[nj], acc[mi][nj], 0,0,0);
    __syncthreads();
  }

  // epilogue: pair an/ag via shfl_xor(1), highway + lint dot
  float bnv[4], bgv[4], lwv[4]; int qv[4];
  #pragma unroll
  for (int nj=0;nj<4;nj++){
    int q = (wn*64 + nj*16 + l15) >> 1;
    qv[nj] = q;
    int nf = nc*64 + q;
    bnv[nj] = bn[nf]; bgv[nj] = bg[nf]; lwv[nj] = lintW[nf];
  }
  float lmask = (l15 & 1) ? 0.f : 1.f;
  float sc[4][4];
  #pragma unroll
  for (int mi=0;mi<4;mi++)
    #pragma unroll
    for (int r=0;r<4;r++) sc[mi][r] = 0.f;

  #pragma unroll
  for (int nj=0;nj<4;nj++){
    int q = qv[nj];
    int cs = q >> 5, kk = q & 31, gor = kk >> 3, el = kk & 7;
    #pragma unroll
    for (int mi=0;mi<4;mi++){
      int mbase = wm*64 + mi*16 + lq*4;
      #pragma unroll
      for (int r=0;r<4;r++){
        float v  = acc[mi][nj][r];
        float pv = __shfl_xor(v, 1);
        int mm = mbase + r;
        unsigned short cu = (unsigned short)Asave[cs*4096 + mm*32 + TK_SWZ(gor,mm)*8 + el];
        float cmf = __uint_as_float(((unsigned int)cu) << 16);
        float an = v + bnv[nj];
        float ag = pv + bgv[nj];
        float gg = sigmoidf_(ag);
        float hw = fmaxf(an, 0.f)*gg + (1.f - gg)*cmf;
        sc[mi][r] += lmask * lwv[nj] * hw;
      }
    }
  }
  // reduce over the 16 lanes of each quad-row group
  #pragma unroll
  for (int mi=0;mi<4;mi++)
    #pragma unroll
    for (int r=0;r<4;r++){
      float v = sc[mi][r];
      v += __shfl_xor(v, 1); v += __shfl_xor(v, 2);
      v += __shfl_xor(v, 4); v += __shfl_xor(v, 8);
      sc[mi][r] = v;
    }
  if (l15 == 0){
    #pragma unroll
    for (int mi=0;mi<4;mi++)
      #pragma unroll
      for (int r=0;r<4;r++)
        sred[(wm*64 + mi*16 + lq*4 + r)*2 + wn] = sc[mi][r];
  }
  __syncthreads();
  if (tid < 128){
    float v = sred[tid*2] + sred[tid*2+1];
    int isel = tid >> 6, j = tid & 63;
    P[(((size_t)nc*16 + b)*64 + (ip*2 + isel))*64 + j] = v;
  }
}

__global__ void k_score_reduce(const float* __restrict__ P, float* __restrict__ S){
  int idx = blockIdx.x*256 + threadIdx.x;  // 65536
  float v = 0.f;
  #pragma unroll
  for (int nc = 0; nc < 8; nc++) v += P[(size_t)nc*65536 + idx];
  S[idx] = v;
}

// ---------------- softmaxes over j (w_l) and over i (w_r) ----------------
__global__ void k_softmax_wl(const float* __restrict__ S, const float* __restrict__ TM,
                             float* __restrict__ WLo){
  int i = blockIdx.x, b = blockIdx.y, j = threadIdx.x;
  float mask = TM[1024 + b*64 + j];
  float v = S[((size_t)b*64 + i)*64 + j] + (mask != 0.f ? 0.f : -1e10f);
  float m = v;
  for (int o = 32; o; o >>= 1) m = fmaxf(m, __shfl_xor(m, o));
  float e = expf(v - m), s = e;
  for (int o = 32; o; o >>= 1) s += __shfl_xor(s, o);
  WLo[((size_t)b*64 + i)*64 + j] = e / s;
}
__global__ void k_softmax_wr(const float* __restrict__ S, const float* __restrict__ TM,
                             float* __restrict__ WRo){
  int j = blockIdx.x, b = blockIdx.y, i = threadIdx.x;
  float mask = TM[b*64 + i];
  float v = S[((size_t)b*64 + i)*64 + j] + (mask != 0.f ? 0.f : -1e10f);
  float m = v;
  for (int o = 32; o; o >>= 1) m = fmaxf(m, __shfl_xor(m, o));
  float e = expf(v - m), s = e;
  for (int o = 32; o; o >>= 1) s += __shfl_xor(s, o);
  WRo[((size_t)b*64 + j)*64 + i] = e / s;
}

// ---------------- weighted |L-R| sums ----------------
__global__ __launch_bounds__(256) void k_cmp(const float* __restrict__ Hf,
    const float* __restrict__ w, float* __restrict__ out, int side){
  int p = blockIdx.x, b = blockIdx.y;
  __shared__ float wl[64];
  if (threadIdx.x < 64) wl[threadIdx.x] = w[((size_t)b*64 + p)*64 + threadIdx.x];
  __syncthreads();
  int xr = tokrow(side, b, p);
  int d1 = threadIdx.x, d2 = threadIdx.x + 256;
  float x1 = Hf[(size_t)xr*NH2 + d1], x2 = Hf[(size_t)xr*NH2 + d2];
  float a1 = 0.f, a2 = 0.f;
  for (int q = 0; q < 64; q++){
    const float* yr = Hf + (size_t)tokrow(side^1, b, q)*NH2;
    float wq = wl[q];
    a1 += wq * fabsf(x1 - yr[d1]);
    a2 += wq * fabsf(x2 - yr[d2]);
  }
  out[((size_t)b*64 + p)*NH2 + d1] = a1;
  out[((size_t)b*64 + p)*NH2 + d2] = a2;
}

// ---------------- attribute matching -> concat buffer ----------------
__global__ __launch_bounds__(256) void k_attr(const float* __restrict__ Hf,
    const float* __restrict__ attrL, const float* __restrict__ attrR,
    const float* __restrict__ LC, const float* __restrict__ RC,
    const float* __restrict__ TM, const float* __restrict__ AM,
    const float* __restrict__ emptyA, float* __restrict__ CC){
  int fi = blockIdx.x, b = blockIdx.y, side = blockIdx.z;
  const float* attr = (side ? attrR : attrL) + fi*512;
  const float* cmp = side ? RC : LC;
  __shared__ float sc[32], wv[32];
  int t = threadIdx.x >> 3, l8 = threadIdx.x & 7;
  const float* er = Hf + (size_t)tokrow(side, b, fi*32 + t)*NH2;
  float acc = 0.f;
  for (int d = l8*64; d < l8*64 + 64; d++) acc += er[d]*attr[d];
  acc += __shfl_down(acc, 4, 8);
  acc += __shfl_down(acc, 2, 8);
  acc += __shfl_down(acc, 1, 8);
  if (l8 == 0) sc[t] = acc;
  __syncthreads();
  if (threadIdx.x < 32){
    float mask = TM[side*1024 + b*64 + fi*32 + threadIdx.x];
    float v = sc[threadIdx.x] + (mask != 0.f ? 0.f : -1e10f);
    float m = v;
    for (int o = 16; o; o >>= 1) m = fmaxf(m, __shfl_xor(m, o, 32));
    float e = expf(v - m), s = e;
    for (int o = 16; o; o >>= 1) s += __shfl_xor(s, o, 32);
    wv[threadIdx.x] = e / s;
  }
  __syncthreads();
  float am = AM[side*32 + b*2 + fi];
  int d1 = threadIdx.x, d2 = threadIdx.x + 256;
  float a1 = 0.f, a2 = 0.f;
  for (int t2 = 0; t2 < 32; t2++){
    float wq = wv[t2];
    const float* cr = cmp + ((size_t)b*64 + fi*32 + t2)*NH2;
    a1 += wq * cr[d1];
    a2 += wq * cr[d2];
  }
  float* dst = CC + (size_t)b*NDE + (size_t)(side*2 + fi)*512;
  dst[d1] = (am != 0.f) ? a1 : emptyA[d1];
  dst[d2] = (am != 0.f) ? a2 : emptyA[d2];
}

// ---------------- final highway (2048x2048) ----------------
__global__ __launch_bounds__(256) void k_final_hw(const float* __restrict__ X,
    const float* __restrict__ Wn, const float* __restrict__ bn,
    const float* __restrict__ Wg, const float* __restrict__ bg,
    float* __restrict__ HWo){
  __shared__ float Xs[4][2048];
  int nb = blockIdx.x, bq = blockIdx.y;
  for (int idx = threadIdx.x; idx < 8192; idx += 256)
    Xs[idx>>11][idx & 2047] = X[(size_t)(bq*4 + (idx>>11))*NDE + (idx & 2047)];
  __syncthreads();
  int nl = threadIdx.x >> 1, kl = threadIdx.x & 1;
  int n = nb*128 + nl;
  const float* wnr = Wn + (size_t)n*NDE + kl*1024;
  const float* wgr = Wg + (size_t)n*NDE + kl*1024;
  float an[4] = {0,0,0,0}, ag[4] = {0,0,0,0};
  for (int k = 0; k < 1024; k++){
    float wn = wnr[k], wg = wgr[k];
    int kk = kl*1024 + k;
    #pragma unroll
    for (int b4 = 0; b4 < 4; b4++){
      float xv = Xs[b4][kk];
      an[b4] = fmaf(wn, xv, an[b4]);
      ag[b4] = fmaf(wg, xv, ag[b4]);
    }
  }
  #pragma unroll
  for (int b4 = 0; b4 < 4; b4++){
    an[b4] += __shfl_down(an[b4], 1);
    ag[b4] += __shfl_down(ag[b4], 1);
  }
  if (kl == 0){
    float bnv = bn[n], bgv = bg[n];
    #pragma unroll
    for (int b4 = 0; b4 < 4; b4++){
      float a = an[b4] + bnv;
      float g = sigmoidf_(ag[b4] + bgv);
      float xv = Xs[b4][n];
      HWo[(size_t)(bq*4 + b4)*NDE + n] = fmaxf(a, 0.f)*g + (1.f - g)*xv;
    }
  }
}

// ---------------- linear + log_softmax ----------------
__global__ void k_out(const float* __restrict__ HWi, const float* __restrict__ lw,
                      const float* __restrict__ lb, float* __restrict__ out){
  int b = blockIdx.x, lane = threadIdx.x;
  float p0 = 0.f, p1 = 0.f;
  for (int n = lane; n < 2048; n += 64){
    float h = HWi[(size_t)b*NDE + n];
    p0 += h * lw[n];
    p1 += h * lw[2048 + n];
  }
  for (int o = 32; o; o >>= 1){ p0 += __shfl_xor(p0, o); p1 += __shfl_xor(p1, o); }
  if (lane == 0){
    float o0 = p0 + lb[0], o1 = p1 + lb[1];
    float m = fmaxf(o0, o1);
    float lse = m + logf(expf(o0 - m) + expf(o1 - m));
    out[b*2]   = o0 - lse;
    out[b*2+1] = o1 - lse;
  }
}

extern "C" void kernel_launch(void* const* d_in, const int* in_sizes, int n_in,
                              void* d_out, int out_size, void* d_ws, size_t ws_size,
                              hipStream_t stream){
  const float* lf0 = (const float*)d_in[0];
  const float* lf1 = (const float*)d_in[1];
  const float* rf0 = (const float*)d_in[2];
  const float* rf1 = (const float*)d_in[3];
  const float* gWih0 = (const float*)d_in[4];
  const float* gWhh0 = (const float*)d_in[5];
  const float* gbih0 = (const float*)d_in[6];
  const float* gbhh0 = (const float*)d_in[7];
  const float* gWih12 = (const float*)d_in[8];
  const float* gWhh12 = (const float*)d_in[9];
  const float* gbih12 = (const float*)d_in[10];
  const float* gbhh12 = (const float*)d_in[11];
  const float* hwtWn = (const float*)d_in[12];
  const float* hwtbn = (const float*)d_in[13];
  const float* hwtWg = (const float*)d_in[14];
  const float* hwtbg = (const float*)d_in[15];
  const float* lintW = (const float*)d_in[16];
  // d_in[17] = lintB (dropped: softmax is shift-invariant)
  const float* attrL = (const float*)d_in[18];
  const float* attrR = (const float*)d_in[19];
  const float* emptyA = (const float*)d_in[20];
  const float* hweWn = (const float*)d_in[21];
  const float* hwebn = (const float*)d_in[22];
  const float* hweWg = (const float*)d_in[23];
  const float* hwebg = (const float*)d_in[24];
  const float* lineW = (const float*)d_in[25];
  const float* lineB = (const float*)d_in[26];
  float* out = (float*)d_out;

  float* ws = (float*)d_ws;
  float* X0   = ws;                         // 2048*768
  float* XI   = X0 + (size_t)NBT*NE;        // 2*2048*768 (also aliased by P later)
  float* HA   = XI + (size_t)2*NBT*NG3;     // 2048*512
  float* HB   = HA + (size_t)NBT*NH2;       // 2048*512
  unsigned short* WHH = (unsigned short*)(HB + (size_t)NBT*NH2); // 6*768*256 bf16
  unsigned short* TW  = WHH + (size_t)6*NG3*NH;                  // 524288 bf16
  float* Sb   = (float*)(TW + 524288);
  float* WLb  = Sb  + 16*64*64;
  float* WRb  = WLb + 16*64*64;
  float* LC   = WRb + 16*64*64;
  float* RC   = LC + (size_t)16*64*512;
  float* TM   = RC + (size_t)16*64*512;
  float* AM   = TM + 2*16*64;
  float* CC   = AM + 64;
  float* HWb  = CC + 16*2048;
  float* P    = XI;  // alias: XI is dead after the last scan

  k_gather<<<NBT, 256, 0, stream>>>(lf0, lf1, rf0, rf1, X0);
  k_masks<<<dim3(4,16), 256, 0, stream>>>(lf0, lf1, rf0, rf1, TM, AM);
  k_prep_whh<<<4608, 256, 0, stream>>>(gWhh0, gWhh12, WHH);
  k_prep_tw<<<2048, 256, 0, stream>>>(hwtWn, hwtWg, TW);

  // layer 0
  k_gemm_mfma<<<dim3(6,16,2), 256, 0, stream>>>(X0, gWih0, (long)NG3*NE, gbih0, NG3,
                                                XI, (long)NBT*NG3, NBT, NG3, NE);
  k_scan<<<dim3(64,2), 256, 0, stream>>>(XI, WHH, gbhh0, NG3, HA, 0);
  // layer 1
  k_gemm_mfma<<<dim3(6,16,2), 256, 0, stream>>>(HA, gWih12, (long)NG3*NH2, gbih12, NG3,
                                                XI, (long)NBT*NG3, NBT, NG3, NH2);
  k_scan<<<dim3(64,2), 256, 0, stream>>>(XI, WHH, gbhh12, NG3, HB, 2);
  // layer 2
  k_gemm_mfma<<<dim3(6,16,2), 256, 0, stream>>>(HB, gWih12 + (size_t)2*NG3*NH2, (long)NG3*NH2,
                                                gbih12 + 2*NG3, NG3,
                                                XI, (long)NBT*NG3, NBT, NG3, NH2);
  k_scan<<<dim3(64,2), 256, 0, stream>>>(XI, WHH, gbhh12 + 2*NG3, NG3, HA, 4);

  // token matching (MFMA) -> partials -> scores
  k_token_mfma<<<dim3(32,16,8), 256, 0, stream>>>(HA, TW, hwtbn, hwtbg, lintW, P);
  k_score_reduce<<<256, 256, 0, stream>>>(P, Sb);
  k_softmax_wl<<<dim3(64,16), 64, 0, stream>>>(Sb, TM, WLb);
  k_softmax_wr<<<dim3(64,16), 64, 0, stream>>>(Sb, TM, WRb);
  k_cmp<<<dim3(64,16), 256, 0, stream>>>(HA, WLb, LC, 0);
  k_cmp<<<dim3(64,16), 256, 0, stream>>>(HA, WRb, RC, 1);

  // attribute matching -> concat
  k_attr<<<dim3(2,16,2), 256, 0, stream>>>(HA, attrL, attrR, LC, RC, TM, AM, emptyA, CC);

  // final highway + classifier
  k_final_hw<<<dim3(16,4), 256, 0, stream>>>(CC, hweWn, hwebn, hweWg, hwebg, HWb);
  k_out<<<16, 64, 0, stream>>>(HWb, lineW, lineB, out);
}

// Round 3
// 1073.650 us; speedup vs baseline: 3.4998x; 1.6295x over previous
//
#include <hip/hip_runtime.h>
#include <hip/hip_bf16.h>

#define NH 256      // H
#define NE 768      // E
#define NH2 512
#define NG3 768     // 3*H
#define NB 16
#define NLF 32
#define NBT 2048    // 4 fields * 16 * 32 rows
#define NDE 2048

typedef short s16x8 __attribute__((ext_vector_type(8)));
typedef float f32x4 __attribute__((ext_vector_type(4)));

// swizzle: granule g (8 bf16) of row r stored at position (g + (r>>1)) & 3
#define TK_SWZ(g, r) (((g) + ((r) >> 1)) & 3)

__device__ __forceinline__ float sigmoidf_(float x){ return 1.f/(1.f+expf(-x)); }
__device__ __forceinline__ unsigned short f2bf_(float f){
  unsigned int x = __float_as_uint(f);
  unsigned int r = (x + 0x7fffu + ((x>>16)&1u)) >> 16;
  return (unsigned short)r;
}
// pack 2 floats to 2 bf16 (round-half-up) in one u32: low=a, high=b
__device__ __forceinline__ unsigned int pack_bf16_rnd(float a, float b){
  unsigned int ua = __float_as_uint(a) + 0x8000u;
  unsigned int ub = __float_as_uint(b) + 0x8000u;
  return __builtin_amdgcn_perm(ub, ua, 0x07060302u);
}
// row in the (2048 x 512) embedding buffer for (side, b, tok)
__device__ __forceinline__ int tokrow(int side, int b, int tok){
  return (((side*2 + (tok>>5))*16 + b) << 5) + (tok & 31);
}

// ---------------- gather 4 fields into X0 (2048 x 768) ----------------
__global__ void k_gather(const float* __restrict__ f0, const float* __restrict__ f1,
                         const float* __restrict__ f2, const float* __restrict__ f3,
                         float* __restrict__ X0){
  int m = blockIdx.x;
  int f = m >> 9, rem = m & 511;
  const float* src = (f==0)? f0 : (f==1)? f1 : (f==2)? f2 : f3;
  const float* sp = src + (size_t)rem*NE;
  float* dp = X0 + (size_t)m*NE;
  for (int d = threadIdx.x; d < NE; d += 256) dp[d] = sp[d];
}

// ---------------- token & attribute masks ----------------
__global__ void k_masks(const float* __restrict__ f0, const float* __restrict__ f1,
                        const float* __restrict__ f2, const float* __restrict__ f3,
                        float* __restrict__ TM, float* __restrict__ AM){
  int f = blockIdx.x, b = blockIdx.y;
  const float* src = (f==0)? f0 : (f==1)? f1 : (f==2)? f2 : f3;
  __shared__ unsigned int flags[33];
  if (threadIdx.x < 33) flags[threadIdx.x] = 0u;
  __syncthreads();
  for (int t = 0; t < 32; t++){
    const float* row = src + ((size_t)b*NLF + t)*NE;
    bool nz = false;
    for (int d = threadIdx.x; d < NE; d += 256) nz |= (row[d] != 0.f);
    if (nz) atomicOr(&flags[t], 1u);
  }
  __syncthreads();
  int side = f >> 1, fi = f & 1;
  if (threadIdx.x < 32){
    unsigned int fl = flags[threadIdx.x];
    TM[side*1024 + b*64 + fi*32 + threadIdx.x] = fl ? 1.f : 0.f;
    if (fl) atomicOr(&flags[32], 1u);
  }
  __syncthreads();
  if (threadIdx.x == 0) AM[side*32 + b*2 + fi] = flags[32] ? 1.f : 0.f;
}

// ---------------- convert all 6 Whh chains to bf16 ----------------
__global__ void k_prep_whh(const float* __restrict__ w0, const float* __restrict__ w12,
                           unsigned short* __restrict__ dst){
  int idx = blockIdx.x*256 + threadIdx.x;   // < 1179648
  float v = (idx < 393216) ? w0[idx] : w12[idx - 393216];
  dst[idx] = f2bf_(v);
}

// ---------------- prep token weights: TW[nc][kc][n(interleaved)][k32] bf16, pre-swizzled ----------------
__global__ void k_prep_tw(const float* __restrict__ Wn, const float* __restrict__ Wg,
                          unsigned short* __restrict__ TW){
  int idx = blockIdx.x*256 + threadIdx.x;   // < 524288
  int kpos = idx & 31;
  int n    = (idx >> 5) & 127;
  int kc   = (idx >> 12) & 15;
  int nc   = idx >> 16;
  int gpos = kpos >> 3, j = kpos & 7;
  int gorig = (gpos - (n>>1)) & 3;
  int k = kc*32 + gorig*8 + j;
  int q = n >> 1, type = n & 1;
  const float* src = type ? Wg : Wn;
  TW[idx] = f2bf_(src[(size_t)(nc*64 + q)*NH2 + k]);
}

// ---------------- bf16 MFMA NT GEMM: C[z] = A @ W[z]^T + bias[z]; 128x128 tile ----------------
__global__ __launch_bounds__(256) void k_gemm_mfma(
    const float* __restrict__ A,
    const float* __restrict__ Wb, long wsz,
    const float* __restrict__ biasb, long bsz,
    float* __restrict__ Cb, long csz,
    int M, int N, int K)
{
  int z = blockIdx.z;
  const float* W = Wb + (size_t)z*wsz;
  const float* bias = biasb + (size_t)z*bsz;
  float* C = Cb + (size_t)z*csz;
  int n0 = blockIdx.x*128, m0 = blockIdx.y*128;
  __shared__ short At[128*32];
  __shared__ short Wt[128*32];
  int tid = threadIdx.x;
  int wave = tid >> 6, wm = wave >> 1, wn = wave & 1;
  int lane = tid & 63, l15 = lane & 15, lq = lane >> 4;
  int sm = tid & 127, gb = (tid >> 7) * 2;

  f32x4 zero4 = {0.f,0.f,0.f,0.f};
  f32x4 acc[4][4];
  #pragma unroll
  for (int mi=0;mi<4;mi++)
    #pragma unroll
    for (int nj=0;nj<4;nj++) acc[mi][nj] = zero4;

  const float* ar = A + (size_t)(m0 + sm)*K;
  const float* wr = W + (size_t)(n0 + sm)*K;

  for (int k0 = 0; k0 < K; k0 += 32){
    #pragma unroll
    for (int gi = 0; gi < 2; gi++){
      int g = gb + gi;
      const float* ap = ar + k0 + g*8;
      float4 a0 = *(const float4*)ap, a1 = *(const float4*)(ap+4);
      uint4 pa = { pack_bf16_rnd(a0.x,a0.y), pack_bf16_rnd(a0.z,a0.w),
                   pack_bf16_rnd(a1.x,a1.y), pack_bf16_rnd(a1.z,a1.w) };
      *(uint4*)&At[sm*32 + TK_SWZ(g,sm)*8] = pa;
      const float* wp = wr + k0 + g*8;
      float4 w0 = *(const float4*)wp, w1 = *(const float4*)(wp+4);
      uint4 pw = { pack_bf16_rnd(w0.x,w0.y), pack_bf16_rnd(w0.z,w0.w),
                   pack_bf16_rnd(w1.x,w1.y), pack_bf16_rnd(w1.z,w1.w) };
      *(uint4*)&Wt[sm*32 + TK_SWZ(g,sm)*8] = pw;
    }
    __syncthreads();
    s16x8 af[4], wf[4];
    #pragma unroll
    for (int mi=0;mi<4;mi++){
      int row = wm*64 + mi*16 + l15;
      af[mi] = *(const s16x8*)&At[row*32 + TK_SWZ(lq,row)*8];
    }
    #pragma unroll
    for (int nj=0;nj<4;nj++){
      int row = wn*64 + nj*16 + l15;
      wf[nj] = *(const s16x8*)&Wt[row*32 + TK_SWZ(lq,row)*8];
    }
    #pragma unroll
    for (int mi=0;mi<4;mi++)
      #pragma unroll
      for (int nj=0;nj<4;nj++)
        acc[mi][nj] = __builtin_amdgcn_mfma_f32_16x16x32_bf16(af[mi], wf[nj], acc[mi][nj], 0,0,0);
    __syncthreads();
  }
  // epilogue: C[m][n] = acc + bias[n]; D layout: n = l&15, m = lq*4 + reg
  #pragma unroll
  for (int nj=0;nj<4;nj++){
    int n = n0 + wn*64 + nj*16 + l15;
    float bv = bias[n];
    #pragma unroll
    for (int mi=0;mi<4;mi++){
      int mbase = m0 + wm*64 + mi*16 + lq*4;
      #pragma unroll
      for (int r=0;r<4;r++)
        C[(size_t)(mbase + r)*N + n] = acc[mi][nj][r] + bv;
    }
  }
}

// ---------------- GRU scan via MFMA, weights register-resident ----------------
// block = (seq-group g of 16 b', dir). 512 thr = 8 waves. Wave w owns col-tiles
// {w, w+8, w+16, w+24, w+32, w+40} (16 cols each) -> r,z,n for SAME u in SAME thread.
// 48 B-frags = 192 VGPR, loaded once. h double-buffered in LDS (bf16, stride 264).
__global__ __launch_bounds__(512, 2) void k_scan_mfma(
    const float* __restrict__ xi,            // [2][2048][768]
    const unsigned short* __restrict__ whh,  // [6][768][256] bf16
    const float* __restrict__ bhhb, long bhh_stride,
    float* __restrict__ Hout,                // [2048][512]
    int chain0)
{
  int g = blockIdx.x;        // b' in [16g, 16g+16)
  int dir = blockIdx.y;
  int tid = threadIdx.x;
  int w = tid >> 6;
  int lane = tid & 63, l15 = lane & 15, lq = lane >> 4;
  const unsigned short* W = whh + (size_t)(chain0 + dir)*NG3*NH;
  const float* bhh = bhhb + (size_t)dir*bhh_stride;
  const float* xid = xi + (size_t)dir*NBT*NG3;

  __shared__ short hbuf[2*16*264];
  for (int i = tid; i < 2*16*264; i += 512) hbuf[i] = 0;

  // resident weight fragments: tile T = w + 8*p6, col c = 16T + l15
  s16x8 warr[6][8];
  #pragma unroll
  for (int p6 = 0; p6 < 6; p6++){
    const unsigned short* wp = W + (size_t)(16*(w + 8*p6) + l15)*NH + lq*8;
    #pragma unroll
    for (int kt = 0; kt < 8; kt++)
      warr[p6][kt] = *(const s16x8*)(wp + kt*32);
  }
  float brv[2], bzv[2], bnv[2];
  #pragma unroll
  for (int p = 0; p < 2; p++){
    int u = p*128 + 16*w + l15;
    brv[p] = bhh[u]; bzv[p] = bhh[256+u]; bnv[p] = bhh[512+u];
  }
  int b0 = g*16;
  __syncthreads();

  for (int s = 0; s < 32; s++){
    int t = dir ? (31 - s) : s;
    const short* rbp = hbuf + (s & 1)*4224;
    short* wbp = hbuf + ((s & 1)^1)*4224;

    // xi prefetch for pair 0 (12 loads) — overlaps with MFMA
    float xv0[12];
    {
      int u = 16*w + l15;
      #pragma unroll
      for (int r4 = 0; r4 < 4; r4++){
        int xo = ((b0 + lq*4 + r4)*32 + t)*NG3 + u;
        xv0[r4]   = xid[xo];
        xv0[4+r4] = xid[xo+256];
        xv0[8+r4] = xid[xo+512];
      }
    }

    f32x4 acc[6];
    #pragma unroll
    for (int p6 = 0; p6 < 6; p6++) acc[p6] = (f32x4){0.f,0.f,0.f,0.f};
    #pragma unroll
    for (int kt = 0; kt < 8; kt++){
      s16x8 a = *(const s16x8*)&rbp[l15*264 + kt*32 + lq*8];
      #pragma unroll
      for (int p6 = 0; p6 < 6; p6++)
        acc[p6] = __builtin_amdgcn_mfma_f32_16x16x32_bf16(a, warr[p6][kt], acc[p6], 0,0,0);
    }

    // xi prefetch for pair 1 (12 loads) — overlaps with pair-0 epilogue
    float xv1[12];
    {
      int u = 128 + 16*w + l15;
      #pragma unroll
      for (int r4 = 0; r4 < 4; r4++){
        int xo = ((b0 + lq*4 + r4)*32 + t)*NG3 + u;
        xv1[r4]   = xid[xo];
        xv1[4+r4] = xid[xo+256];
        xv1[8+r4] = xid[xo+512];
      }
    }

    #pragma unroll
    for (int p = 0; p < 2; p++){
      int u = p*128 + 16*w + l15;
      const float* xv = p ? xv1 : xv0;
      #pragma unroll
      for (int r4 = 0; r4 < 4; r4++){
        int m = lq*4 + r4;
        float rr = sigmoidf_(xv[r4]   + acc[p][r4]   + brv[p]);
        float zz = sigmoidf_(xv[4+r4] + acc[2+p][r4] + bzv[p]);
        float nn = tanhf(xv[8+r4] + rr*(acc[4+p][r4] + bnv[p]));
        unsigned short ho = (unsigned short)rbp[m*264 + u];
        float hold = __uint_as_float(((unsigned int)ho) << 16);
        float hnew = (1.f - zz)*nn + zz*hold;
        wbp[m*264 + u] = (short)f2bf_(hnew);
        Hout[((b0 + m)*32 + t)*NH2 + dir*256 + u] = hnew;
      }
    }
    __syncthreads();
  }
}

// ---------------- token-matching scores via MFMA: partials P[nc][b][i][j] ----------------
__global__ __launch_bounds__(256) void k_token_mfma(
    const float* __restrict__ Hf,
    const unsigned short* __restrict__ TW,   // [8][16][128][32] bf16 pre-swizzled
    const float* __restrict__ bn, const float* __restrict__ bg,
    const float* __restrict__ lintW,
    float* __restrict__ P)
{
  __shared__ short Atile[128*32];
  __shared__ short Btile[128*32];
  __shared__ short Asave[2*128*32];
  __shared__ float sred[256];
  int ip = blockIdx.x, b = blockIdx.y, nc = blockIdx.z;
  int tid = threadIdx.x;
  int wave = tid >> 6, wm = wave >> 1, wn = wave & 1;
  int lane = tid & 63, l15 = lane & 15, lq = lane >> 4;
  int m = tid & 127, gb = (tid >> 7) * 2;
  int i_ = ip*2 + (m >> 6), j_ = m & 63;
  const float* Lrow = Hf + (size_t)tokrow(0, b, i_)*NH2;
  const float* Rrow = Hf + (size_t)tokrow(1, b, j_)*NH2;
  const uint4* TWu = (const uint4*)TW + ((size_t)(nc*16))*512;

  f32x4 zero4 = {0.f,0.f,0.f,0.f};
  f32x4 acc[4][4];
  #pragma unroll
  for (int mi=0;mi<4;mi++)
    #pragma unroll
    for (int nj=0;nj<4;nj++) acc[mi][nj] = zero4;

  for (int kc = 0; kc < 16; kc++){
    int k0 = kc*32;
    // build A-tile (cm = |L - R|, bf16)
    #pragma unroll
    for (int gi = 0; gi < 2; gi++){
      int g = gb + gi;
      const float* lp = Lrow + k0 + g*8;
      const float* rp = Rrow + k0 + g*8;
      float4 l0 = *(const float4*)lp, l1 = *(const float4*)(lp+4);
      float4 r0 = *(const float4*)rp, r1 = *(const float4*)(rp+4);
      uint4 pk = { pack_bf16_rnd(fabsf(l0.x-r0.x), fabsf(l0.y-r0.y)),
                   pack_bf16_rnd(fabsf(l0.z-r0.z), fabsf(l0.w-r0.w)),
                   pack_bf16_rnd(fabsf(l1.x-r1.x), fabsf(l1.y-r1.y)),
                   pack_bf16_rnd(fabsf(l1.z-r1.z), fabsf(l1.w-r1.w)) };
      int woff = m*32 + TK_SWZ(g,m)*8;
      *(uint4*)&Atile[woff] = pk;
      int cs = kc - 2*nc;
      if ((unsigned)cs < 2u) *(uint4*)&Asave[cs*4096 + woff] = pk;
    }
    // stage B-tile (straight copy; layout pre-swizzled in prep)
    {
      const uint4* src = TWu + (size_t)kc*512;
      ((uint4*)Btile)[tid*2]   = src[tid*2];
      ((uint4*)Btile)[tid*2+1] = src[tid*2+1];
    }
    __syncthreads();
    s16x8 af[4], bfv[4];
    #pragma unroll
    for (int mi=0;mi<4;mi++){
      int row = wm*64 + mi*16 + l15;
      af[mi] = *(const s16x8*)&Atile[row*32 + TK_SWZ(lq,row)*8];
    }
    #pragma unroll
    for (int nj=0;nj<4;nj++){
      int row = wn*64 + nj*16 + l15;
      bfv[nj] = *(const s16x8*)&Btile[row*32 + TK_SWZ(lq,row)*8];
    }
    #pragma unroll
    for (int mi=0;mi<4;mi++)
      #pragma unroll
      for (int nj=0;nj<4;nj++)
        acc[mi][nj] = __builtin_amdgcn_mfma_f32_16x16x32_bf16(af[mi], bfv[nj], acc[mi][nj], 0,0,0);
    __syncthreads();
  }

  // epilogue: pair an/ag via shfl_xor(1), highway + lint dot
  float bnv[4], bgv[4], lwv[4]; int qv[4];
  #pragma unroll
  for (int nj=0;nj<4;nj++){
    int q = (wn*64 + nj*16 + l15) >> 1;
    qv[nj] = q;
    int nf = nc*64 + q;
    bnv[nj] = bn[nf]; bgv[nj] = bg[nf]; lwv[nj] = lintW[nf];
  }
  float lmask = (l15 & 1) ? 0.f : 1.f;
  float sc[4][4];
  #pragma unroll
  for (int mi=0;mi<4;mi++)
    #pragma unroll
    for (int r=0;r<4;r++) sc[mi][r] = 0.f;

  #pragma unroll
  for (int nj=0;nj<4;nj++){
    int q = qv[nj];
    int cs = q >> 5, kk = q & 31, gor = kk >> 3, el = kk & 7;
    #pragma unroll
    for (int mi=0;mi<4;mi++){
      int mbase = wm*64 + mi*16 + lq*4;
      #pragma unroll
      for (int r=0;r<4;r++){
        float v  = acc[mi][nj][r];
        float pv = __shfl_xor(v, 1);
        int mm = mbase + r;
        unsigned short cu = (unsigned short)Asave[cs*4096 + mm*32 + TK_SWZ(gor,mm)*8 + el];
        float cmf = __uint_as_float(((unsigned int)cu) << 16);
        float an = v + bnv[nj];
        float ag = pv + bgv[nj];
        float gg = sigmoidf_(ag);
        float hw = fmaxf(an, 0.f)*gg + (1.f - gg)*cmf;
        sc[mi][r] += lmask * lwv[nj] * hw;
      }
    }
  }
  #pragma unroll
  for (int mi=0;mi<4;mi++)
    #pragma unroll
    for (int r=0;r<4;r++){
      float v = sc[mi][r];
      v += __shfl_xor(v, 1); v += __shfl_xor(v, 2);
      v += __shfl_xor(v, 4); v += __shfl_xor(v, 8);
      sc[mi][r] = v;
    }
  if (l15 == 0){
    #pragma unroll
    for (int mi=0;mi<4;mi++)
      #pragma unroll
      for (int r=0;r<4;r++)
        sred[(wm*64 + mi*16 + lq*4 + r)*2 + wn] = sc[mi][r];
  }
  __syncthreads();
  if (tid < 128){
    float v = sred[tid*2] + sred[tid*2+1];
    int isel = tid >> 6, j = tid & 63;
    P[(((size_t)nc*16 + b)*64 + (ip*2 + isel))*64 + j] = v;
  }
}

__global__ void k_score_reduce(const float* __restrict__ P, float* __restrict__ S){
  int idx = blockIdx.x*256 + threadIdx.x;  // 65536
  float v = 0.f;
  #pragma unroll
  for (int nc = 0; nc < 8; nc++) v += P[(size_t)nc*65536 + idx];
  S[idx] = v;
}

// ---------------- softmaxes over j (w_l) and over i (w_r) ----------------
__global__ void k_softmax_wl(const float* __restrict__ S, const float* __restrict__ TM,
                             float* __restrict__ WLo){
  int i = blockIdx.x, b = blockIdx.y, j = threadIdx.x;
  float mask = TM[1024 + b*64 + j];
  float v = S[((size_t)b*64 + i)*64 + j] + (mask != 0.f ? 0.f : -1e10f);
  float m = v;
  for (int o = 32; o; o >>= 1) m = fmaxf(m, __shfl_xor(m, o));
  float e = expf(v - m), s = e;
  for (int o = 32; o; o >>= 1) s += __shfl_xor(s, o);
  WLo[((size_t)b*64 + i)*64 + j] = e / s;
}
__global__ void k_softmax_wr(const float* __restrict__ S, const float* __restrict__ TM,
                             float* __restrict__ WRo){
  int j = blockIdx.x, b = blockIdx.y, i = threadIdx.x;
  float mask = TM[b*64 + i];
  float v = S[((size_t)b*64 + i)*64 + j] + (mask != 0.f ? 0.f : -1e10f);
  float m = v;
  for (int o = 32; o; o >>= 1) m = fmaxf(m, __shfl_xor(m, o));
  float e = expf(v - m), s = e;
  for (int o = 32; o; o >>= 1) s += __shfl_xor(s, o);
  WRo[((size_t)b*64 + j)*64 + i] = e / s;
}

// ---------------- weighted |L-R| sums ----------------
__global__ __launch_bounds__(256) void k_cmp(const float* __restrict__ Hf,
    const float* __restrict__ w, float* __restrict__ out, int side){
  int p = blockIdx.x, b = blockIdx.y;
  __shared__ float wl[64];
  if (threadIdx.x < 64) wl[threadIdx.x] = w[((size_t)b*64 + p)*64 + threadIdx.x];
  __syncthreads();
  int xr = tokrow(side, b, p);
  int d1 = threadIdx.x, d2 = threadIdx.x + 256;
  float x1 = Hf[(size_t)xr*NH2 + d1], x2 = Hf[(size_t)xr*NH2 + d2];
  float a1 = 0.f, a2 = 0.f;
  for (int q = 0; q < 64; q++){
    const float* yr = Hf + (size_t)tokrow(side^1, b, q)*NH2;
    float wq = wl[q];
    a1 += wq * fabsf(x1 - yr[d1]);
    a2 += wq * fabsf(x2 - yr[d2]);
  }
  out[((size_t)b*64 + p)*NH2 + d1] = a1;
  out[((size_t)b*64 + p)*NH2 + d2] = a2;
}

// ---------------- attribute matching -> concat buffer ----------------
__global__ __launch_bounds__(256) void k_attr(const float* __restrict__ Hf,
    const float* __restrict__ attrL, const float* __restrict__ attrR,
    const float* __restrict__ LC, const float* __restrict__ RC,
    const float* __restrict__ TM, const float* __restrict__ AM,
    const float* __restrict__ emptyA, float* __restrict__ CC){
  int fi = blockIdx.x, b = blockIdx.y, side = blockIdx.z;
  const float* attr = (side ? attrR : attrL) + fi*512;
  const float* cmp = side ? RC : LC;
  __shared__ float sc[32], wv[32];
  int t = threadIdx.x >> 3, l8 = threadIdx.x & 7;
  const float* er = Hf + (size_t)tokrow(side, b, fi*32 + t)*NH2;
  float acc = 0.f;
  for (int d = l8*64; d < l8*64 + 64; d++) acc += er[d]*attr[d];
  acc += __shfl_down(acc, 4, 8);
  acc += __shfl_down(acc, 2, 8);
  acc += __shfl_down(acc, 1, 8);
  if (l8 == 0) sc[t] = acc;
  __syncthreads();
  if (threadIdx.x < 32){
    float mask = TM[side*1024 + b*64 + fi*32 + threadIdx.x];
    float v = sc[threadIdx.x] + (mask != 0.f ? 0.f : -1e10f);
    float m = v;
    for (int o = 16; o; o >>= 1) m = fmaxf(m, __shfl_xor(m, o, 32));
    float e = expf(v - m), s = e;
    for (int o = 16; o; o >>= 1) s += __shfl_xor(s, o, 32);
    wv[threadIdx.x] = e / s;
  }
  __syncthreads();
  float am = AM[side*32 + b*2 + fi];
  int d1 = threadIdx.x, d2 = threadIdx.x + 256;
  float a1 = 0.f, a2 = 0.f;
  for (int t2 = 0; t2 < 32; t2++){
    float wq = wv[t2];
    const float* cr = cmp + ((size_t)b*64 + fi*32 + t2)*NH2;
    a1 += wq * cr[d1];
    a2 += wq * cr[d2];
  }
  float* dst = CC + (size_t)b*NDE + (size_t)(side*2 + fi)*512;
  dst[d1] = (am != 0.f) ? a1 : emptyA[d1];
  dst[d2] = (am != 0.f) ? a2 : emptyA[d2];
}

// ---------------- final highway (2048x2048) ----------------
__global__ __launch_bounds__(256) void k_final_hw(const float* __restrict__ X,
    const float* __restrict__ Wn, const float* __restrict__ bn,
    const float* __restrict__ Wg, const float* __restrict__ bg,
    float* __restrict__ HWo){
  __shared__ float Xs[4][2048];
  int nb = blockIdx.x, bq = blockIdx.y;
  for (int idx = threadIdx.x; idx < 8192; idx += 256)
    Xs[idx>>11][idx & 2047] = X[(size_t)(bq*4 + (idx>>11))*NDE + (idx & 2047)];
  __syncthreads();
  int nl = threadIdx.x >> 1, kl = threadIdx.x & 1;
  int n = nb*128 + nl;
  const float* wnr = Wn + (size_t)n*NDE + kl*1024;
  const float* wgr = Wg + (size_t)n*NDE + kl*1024;
  float an[4] = {0,0,0,0}, ag[4] = {0,0,0,0};
  for (int k = 0; k < 1024; k++){
    float wn = wnr[k], wg = wgr[k];
    int kk = kl*1024 + k;
    #pragma unroll
    for (int b4 = 0; b4 < 4; b4++){
      float xv = Xs[b4][kk];
      an[b4] = fmaf(wn, xv, an[b4]);
      ag[b4] = fmaf(wg, xv, ag[b4]);
    }
  }
  #pragma unroll
  for (int b4 = 0; b4 < 4; b4++){
    an[b4] += __shfl_down(an[b4], 1);
    ag[b4] += __shfl_down(ag[b4], 1);
  }
  if (kl == 0){
    float bnv = bn[n], bgv = bg[n];
    #pragma unroll
    for (int b4 = 0; b4 < 4; b4++){
      float a = an[b4] + bnv;
      float g = sigmoidf_(ag[b4] + bgv);
      float xv = Xs[b4][n];
      HWo[(size_t)(bq*4 + b4)*NDE + n] = fmaxf(a, 0.f)*g + (1.f - g)*xv;
    }
  }
}

// ---------------- linear + log_softmax ----------------
__global__ void k_out(const float* __restrict__ HWi, const float* __restrict__ lw,
                      const float* __restrict__ lb, float* __restrict__ out){
  int b = blockIdx.x, lane = threadIdx.x;
  float p0 = 0.f, p1 = 0.f;
  for (int n = lane; n < 2048; n += 64){
    float h = HWi[(size_t)b*NDE + n];
    p0 += h * lw[n];
    p1 += h * lw[2048 + n];
  }
  for (int o = 32; o; o >>= 1){ p0 += __shfl_xor(p0, o); p1 += __shfl_xor(p1, o); }
  if (lane == 0){
    float o0 = p0 + lb[0], o1 = p1 + lb[1];
    float m = fmaxf(o0, o1);
    float lse = m + logf(expf(o0 - m) + expf(o1 - m));
    out[b*2]   = o0 - lse;
    out[b*2+1] = o1 - lse;
  }
}

extern "C" void kernel_launch(void* const* d_in, const int* in_sizes, int n_in,
                              void* d_out, int out_size, void* d_ws, size_t ws_size,
                              hipStream_t stream){
  const float* lf0 = (const float*)d_in[0];
  const float* lf1 = (const float*)d_in[1];
  const float* rf0 = (const float*)d_in[2];
  const float* rf1 = (const float*)d_in[3];
  const float* gWih0 = (const float*)d_in[4];
  const float* gWhh0 = (const float*)d_in[5];
  const float* gbih0 = (const float*)d_in[6];
  const float* gbhh0 = (const float*)d_in[7];
  const float* gWih12 = (const float*)d_in[8];
  const float* gWhh12 = (const float*)d_in[9];
  const float* gbih12 = (const float*)d_in[10];
  const float* gbhh12 = (const float*)d_in[11];
  const float* hwtWn = (const float*)d_in[12];
  const float* hwtbn = (const float*)d_in[13];
  const float* hwtWg = (const float*)d_in[14];
  const float* hwtbg = (const float*)d_in[15];
  const float* lintW = (const float*)d_in[16];
  // d_in[17] = lintB (dropped: softmax is shift-invariant)
  const float* attrL = (const float*)d_in[18];
  const float* attrR = (const float*)d_in[19];
  const float* emptyA = (const float*)d_in[20];
  const float* hweWn = (const float*)d_in[21];
  const float* hwebn = (const float*)d_in[22];
  const float* hweWg = (const float*)d_in[23];
  const float* hwebg = (const float*)d_in[24];
  const float* lineW = (const float*)d_in[25];
  const float* lineB = (const float*)d_in[26];
  float* out = (float*)d_out;

  float* ws = (float*)d_ws;
  float* X0   = ws;                         // 2048*768
  float* XI   = X0 + (size_t)NBT*NE;        // 2*2048*768 (aliased by P later)
  float* HA   = XI + (size_t)2*NBT*NG3;     // 2048*512
  float* HB   = HA + (size_t)NBT*NH2;       // 2048*512
  unsigned short* WHH = (unsigned short*)(HB + (size_t)NBT*NH2); // 6*768*256 bf16
  unsigned short* TW  = WHH + (size_t)6*NG3*NH;                  // 524288 bf16
  float* Sb   = (float*)(TW + 524288);
  float* WLb  = Sb  + 16*64*64;
  float* WRb  = WLb + 16*64*64;
  float* LC   = WRb + 16*64*64;
  float* RC   = LC + (size_t)16*64*512;
  float* TM   = RC + (size_t)16*64*512;
  float* AM   = TM + 2*16*64;
  float* CC   = AM + 64;
  float* HWb  = CC + 16*2048;
  float* P    = XI;  // alias: XI dead after last scan

  k_gather<<<NBT, 256, 0, stream>>>(lf0, lf1, rf0, rf1, X0);
  k_masks<<<dim3(4,16), 256, 0, stream>>>(lf0, lf1, rf0, rf1, TM, AM);
  k_prep_whh<<<4608, 256, 0, stream>>>(gWhh0, gWhh12, WHH);
  k_prep_tw<<<2048, 256, 0, stream>>>(hwtWn, hwtWg, TW);

  // layer 0
  k_gemm_mfma<<<dim3(6,16,2), 256, 0, stream>>>(X0, gWih0, (long)NG3*NE, gbih0, NG3,
                                                XI, (long)NBT*NG3, NBT, NG3, NE);
  k_scan_mfma<<<dim3(4,2), 512, 0, stream>>>(XI, WHH, gbhh0, NG3, HA, 0);
  // layer 1
  k_gemm_mfma<<<dim3(6,16,2), 256, 0, stream>>>(HA, gWih12, (long)NG3*NH2, gbih12, NG3,
                                                XI, (long)NBT*NG3, NBT, NG3, NH2);
  k_scan_mfma<<<dim3(4,2), 512, 0, stream>>>(XI, WHH, gbhh12, NG3, HB, 2);
  // layer 2
  k_gemm_mfma<<<dim3(6,16,2), 256, 0, stream>>>(HB, gWih12 + (size_t)2*NG3*NH2, (long)NG3*NH2,
                                                gbih12 + 2*NG3, NG3,
                                                XI, (long)NBT*NG3, NBT, NG3, NH2);
  k_scan_mfma<<<dim3(4,2), 512, 0, stream>>>(XI, WHH, gbhh12 + 2*NG3, NG3, HA, 4);

  // token matching (MFMA) -> partials -> scores
  k_token_mfma<<<dim3(32,16,8), 256, 0, stream>>>(HA, TW, hwtbn, hwtbg, lintW, P);
  k_score_reduce<<<256, 256, 0, stream>>>(P, Sb);
  k_softmax_wl<<<dim3(64,16), 64, 0, stream>>>(Sb, TM, WLb);
  k_softmax_wr<<<dim3(64,16), 64, 0, stream>>>(Sb, TM, WRb);
  k_cmp<<<dim3(64,16), 256, 0, stream>>>(HA, WLb, LC, 0);
  k_cmp<<<dim3(64,16), 256, 0, stream>>>(HA, WRb, RC, 1);

  // attribute matching -> concat
  k_attr<<<dim3(2,16,2), 256, 0, stream>>>(HA, attrL, attrR, LC, RC, TM, AM, emptyA, CC);

  // final highway + classifier
  k_final_hw<<<dim3(16,4), 256, 0, stream>>>(CC, hweWn, hwebn, hweWg, hwebg, HWb);
  k_out<<<16, 64, 0, stream>>>(HWb, lineW, lineB, out);
}

// Round 4
// 1037.031 us; speedup vs baseline: 3.6234x; 1.0353x over previous
//
#include <hip/hip_runtime.h>
#include <hip/hip_bf16.h>

#define NH 256      // H
#define NE 768      // E
#define NH2 512
#define NG3 768     // 3*H
#define NB 16
#define NLF 32
#define NBT 2048    // 4 fields * 16 * 32 rows
#define NDE 2048

typedef short s16x8 __attribute__((ext_vector_type(8)));
typedef float f32x4 __attribute__((ext_vector_type(4)));

// swizzle: granule g (8 bf16) of row r stored at position (g + (r>>1)) & 3
#define TK_SWZ(g, r) (((g) + ((r) >> 1)) & 3)

#if __has_builtin(__builtin_amdgcn_global_load_lds)
#define GLOAD_LDS16(gp, lp) \
  __builtin_amdgcn_global_load_lds((const __attribute__((address_space(1))) unsigned int*)(gp), \
                                   (__attribute__((address_space(3))) unsigned int*)(lp), 16, 0, 0)
#define HAVE_GLLDS 1
#else
#define HAVE_GLLDS 0
#endif

__device__ __forceinline__ float sigmoidf_(float x){ return 1.f/(1.f+expf(-x)); }
__device__ __forceinline__ unsigned short f2bf_(float f){
  unsigned int x = __float_as_uint(f);
  unsigned int r = (x + 0x7fffu + ((x>>16)&1u)) >> 16;
  return (unsigned short)r;
}
// pack 2 floats to 2 bf16 (round-half-up) in one u32: low=a, high=b
__device__ __forceinline__ unsigned int pack_bf16_rnd(float a, float b){
  unsigned int ua = __float_as_uint(a) + 0x8000u;
  unsigned int ub = __float_as_uint(b) + 0x8000u;
  return __builtin_amdgcn_perm(ub, ua, 0x07060302u);
}
// row in the (2048 x 512) embedding buffer for (side, b, tok)
__device__ __forceinline__ int tokrow(int side, int b, int tok){
  return (((side*2 + (tok>>5))*16 + b) << 5) + (tok & 31);
}

// ---------------- gather 4 fields into X0 (2048 x 768) ----------------
__global__ void k_gather(const float* __restrict__ f0, const float* __restrict__ f1,
                         const float* __restrict__ f2, const float* __restrict__ f3,
                         float* __restrict__ X0){
  int m = blockIdx.x;
  int f = m >> 9, rem = m & 511;
  const float* src = (f==0)? f0 : (f==1)? f1 : (f==2)? f2 : f3;
  const float* sp = src + (size_t)rem*NE;
  float* dp = X0 + (size_t)m*NE;
  for (int d = threadIdx.x; d < NE; d += 256) dp[d] = sp[d];
}

// ---------------- token & attribute masks ----------------
__global__ void k_masks(const float* __restrict__ f0, const float* __restrict__ f1,
                        const float* __restrict__ f2, const float* __restrict__ f3,
                        float* __restrict__ TM, float* __restrict__ AM){
  int f = blockIdx.x, b = blockIdx.y;
  const float* src = (f==0)? f0 : (f==1)? f1 : (f==2)? f2 : f3;
  __shared__ unsigned int flags[33];
  if (threadIdx.x < 33) flags[threadIdx.x] = 0u;
  __syncthreads();
  for (int t = 0; t < 32; t++){
    const float* row = src + ((size_t)b*NLF + t)*NE;
    bool nz = false;
    for (int d = threadIdx.x; d < NE; d += 256) nz |= (row[d] != 0.f);
    if (nz) atomicOr(&flags[t], 1u);
  }
  __syncthreads();
  int side = f >> 1, fi = f & 1;
  if (threadIdx.x < 32){
    unsigned int fl = flags[threadIdx.x];
    TM[side*1024 + b*64 + fi*32 + threadIdx.x] = fl ? 1.f : 0.f;
    if (fl) atomicOr(&flags[32], 1u);
  }
  __syncthreads();
  if (threadIdx.x == 0) AM[side*32 + b*2 + fi] = flags[32] ? 1.f : 0.f;
}

// ---------------- convert all 6 Whh chains to bf16 ----------------
__global__ void k_prep_whh(const float* __restrict__ w0, const float* __restrict__ w12,
                           unsigned short* __restrict__ dst){
  int idx = blockIdx.x*256 + threadIdx.x;   // < 1179648
  float v = (idx < 393216) ? w0[idx] : w12[idx - 393216];
  dst[idx] = f2bf_(v);
}

// ---------------- prep token weights: TW[nc][kc][n(interleaved)][k32] bf16, pre-swizzled ----------------
__global__ void k_prep_tw(const float* __restrict__ Wn, const float* __restrict__ Wg,
                          unsigned short* __restrict__ TW){
  int idx = blockIdx.x*256 + threadIdx.x;   // < 524288
  int kpos = idx & 31;
  int n    = (idx >> 5) & 127;
  int kc   = (idx >> 12) & 15;
  int nc   = idx >> 16;
  int gpos = kpos >> 3, j = kpos & 7;
  int gorig = (gpos - (n>>1)) & 3;
  int k = kc*32 + gorig*8 + j;
  int q = n >> 1, type = n & 1;
  const float* src = type ? Wg : Wn;
  TW[idx] = f2bf_(src[(size_t)(nc*64 + q)*NH2 + k]);
}

// ---------------- bf16 MFMA NT GEMM: C[z] = A @ W[z]^T + bias[z]; 128x128 tile ----------------
__global__ __launch_bounds__(256) void k_gemm_mfma(
    const float* __restrict__ A,
    const float* __restrict__ Wb, long wsz,
    const float* __restrict__ biasb, long bsz,
    float* __restrict__ Cb, long csz,
    int M, int N, int K)
{
  int z = blockIdx.z;
  const float* W = Wb + (size_t)z*wsz;
  const float* bias = biasb + (size_t)z*bsz;
  float* C = Cb + (size_t)z*csz;
  int n0 = blockIdx.x*128, m0 = blockIdx.y*128;
  __shared__ short At[128*32];
  __shared__ short Wt[128*32];
  int tid = threadIdx.x;
  int wave = tid >> 6, wm = wave >> 1, wn = wave & 1;
  int lane = tid & 63, l15 = lane & 15, lq = lane >> 4;
  int sm = tid & 127, gb = (tid >> 7) * 2;

  f32x4 zero4 = {0.f,0.f,0.f,0.f};
  f32x4 acc[4][4];
  #pragma unroll
  for (int mi=0;mi<4;mi++)
    #pragma unroll
    for (int nj=0;nj<4;nj++) acc[mi][nj] = zero4;

  const float* ar = A + (size_t)(m0 + sm)*K;
  const float* wr = W + (size_t)(n0 + sm)*K;

  for (int k0 = 0; k0 < K; k0 += 32){
    #pragma unroll
    for (int gi = 0; gi < 2; gi++){
      int g = gb + gi;
      const float* ap = ar + k0 + g*8;
      float4 a0 = *(const float4*)ap, a1 = *(const float4*)(ap+4);
      uint4 pa = { pack_bf16_rnd(a0.x,a0.y), pack_bf16_rnd(a0.z,a0.w),
                   pack_bf16_rnd(a1.x,a1.y), pack_bf16_rnd(a1.z,a1.w) };
      *(uint4*)&At[sm*32 + TK_SWZ(g,sm)*8] = pa;
      const float* wp = wr + k0 + g*8;
      float4 w0 = *(const float4*)wp, w1 = *(const float4*)(wp+4);
      uint4 pw = { pack_bf16_rnd(w0.x,w0.y), pack_bf16_rnd(w0.z,w0.w),
                   pack_bf16_rnd(w1.x,w1.y), pack_bf16_rnd(w1.z,w1.w) };
      *(uint4*)&Wt[sm*32 + TK_SWZ(g,sm)*8] = pw;
    }
    __syncthreads();
    s16x8 af[4], wf[4];
    #pragma unroll
    for (int mi=0;mi<4;mi++){
      int row = wm*64 + mi*16 + l15;
      af[mi] = *(const s16x8*)&At[row*32 + TK_SWZ(lq,row)*8];
    }
    #pragma unroll
    for (int nj=0;nj<4;nj++){
      int row = wn*64 + nj*16 + l15;
      wf[nj] = *(const s16x8*)&Wt[row*32 + TK_SWZ(lq,row)*8];
    }
    #pragma unroll
    for (int mi=0;mi<4;mi++)
      #pragma unroll
      for (int nj=0;nj<4;nj++)
        acc[mi][nj] = __builtin_amdgcn_mfma_f32_16x16x32_bf16(af[mi], wf[nj], acc[mi][nj], 0,0,0);
    __syncthreads();
  }
  // epilogue: C[m][n] = acc + bias[n]; D layout: n = l&15, m = lq*4 + reg
  #pragma unroll
  for (int nj=0;nj<4;nj++){
    int n = n0 + wn*64 + nj*16 + l15;
    float bv = bias[n];
    #pragma unroll
    for (int mi=0;mi<4;mi++){
      int mbase = m0 + wm*64 + mi*16 + lq*4;
      #pragma unroll
      for (int r=0;r<4;r++)
        C[(size_t)(mbase + r)*N + n] = acc[mi][nj][r] + bv;
    }
  }
}

// ---------------- GRU scan via MFMA, weights register-resident ----------------
__global__ __launch_bounds__(512, 2) void k_scan_mfma(
    const float* __restrict__ xi,            // [2][2048][768]
    const unsigned short* __restrict__ whh,  // [6][768][256] bf16
    const float* __restrict__ bhhb, long bhh_stride,
    float* __restrict__ Hout,                // [2048][512]
    int chain0)
{
  int g = blockIdx.x;        // b' in [16g, 16g+16)
  int dir = blockIdx.y;
  int tid = threadIdx.x;
  int w = tid >> 6;
  int lane = tid & 63, l15 = lane & 15, lq = lane >> 4;
  const unsigned short* W = whh + (size_t)(chain0 + dir)*NG3*NH;
  const float* bhh = bhhb + (size_t)dir*bhh_stride;
  const float* xid = xi + (size_t)dir*NBT*NG3;

  __shared__ short hbuf[2*16*264];
  for (int i = tid; i < 2*16*264; i += 512) hbuf[i] = 0;

  // resident weight fragments: tile T = w + 8*p6, col c = 16T + l15
  s16x8 warr[6][8];
  #pragma unroll
  for (int p6 = 0; p6 < 6; p6++){
    const unsigned short* wp = W + (size_t)(16*(w + 8*p6) + l15)*NH + lq*8;
    #pragma unroll
    for (int kt = 0; kt < 8; kt++)
      warr[p6][kt] = *(const s16x8*)(wp + kt*32);
  }
  float brv[2], bzv[2], bnv[2];
  #pragma unroll
  for (int p = 0; p < 2; p++){
    int u = p*128 + 16*w + l15;
    brv[p] = bhh[u]; bzv[p] = bhh[256+u]; bnv[p] = bhh[512+u];
  }
  int b0 = g*16;
  __syncthreads();

  for (int s = 0; s < 32; s++){
    int t = dir ? (31 - s) : s;
    const short* rbp = hbuf + (s & 1)*4224;
    short* wbp = hbuf + ((s & 1)^1)*4224;

    float xv0[12];
    {
      int u = 16*w + l15;
      #pragma unroll
      for (int r4 = 0; r4 < 4; r4++){
        int xo = ((b0 + lq*4 + r4)*32 + t)*NG3 + u;
        xv0[r4]   = xid[xo];
        xv0[4+r4] = xid[xo+256];
        xv0[8+r4] = xid[xo+512];
      }
    }

    f32x4 acc[6];
    #pragma unroll
    for (int p6 = 0; p6 < 6; p6++) acc[p6] = (f32x4){0.f,0.f,0.f,0.f};
    #pragma unroll
    for (int kt = 0; kt < 8; kt++){
      s16x8 a = *(const s16x8*)&rbp[l15*264 + kt*32 + lq*8];
      #pragma unroll
      for (int p6 = 0; p6 < 6; p6++)
        acc[p6] = __builtin_amdgcn_mfma_f32_16x16x32_bf16(a, warr[p6][kt], acc[p6], 0,0,0);
    }

    float xv1[12];
    {
      int u = 128 + 16*w + l15;
      #pragma unroll
      for (int r4 = 0; r4 < 4; r4++){
        int xo = ((b0 + lq*4 + r4)*32 + t)*NG3 + u;
        xv1[r4]   = xid[xo];
        xv1[4+r4] = xid[xo+256];
        xv1[8+r4] = xid[xo+512];
      }
    }

    #pragma unroll
    for (int p = 0; p < 2; p++){
      int u = p*128 + 16*w + l15;
      const float* xv = p ? xv1 : xv0;
      #pragma unroll
      for (int r4 = 0; r4 < 4; r4++){
        int m = lq*4 + r4;
        float rr = sigmoidf_(xv[r4]   + acc[p][r4]   + brv[p]);
        float zz = sigmoidf_(xv[4+r4] + acc[2+p][r4] + bzv[p]);
        float nn = tanhf(xv[8+r4] + rr*(acc[4+p][r4] + bnv[p]));
        unsigned short ho = (unsigned short)rbp[m*264 + u];
        float hold = __uint_as_float(((unsigned int)ho) << 16);
        float hnew = (1.f - zz)*nn + zz*hold;
        wbp[m*264 + u] = (short)f2bf_(hnew);
        Hout[((b0 + m)*32 + t)*NH2 + dir*256 + u] = hnew;
      }
    }
    __syncthreads();
  }
}

// ---------------- precompute cm tiles: CMT[blk(bl*32+ip)][kc][m128][32] bf16, swizzled ----------------
__global__ __launch_bounds__(256) void k_cm_pretile(
    const float* __restrict__ Hf, unsigned short* __restrict__ CMT, int b0)
{
  int ip = blockIdx.x, bl = blockIdx.y;
  int b = b0 + bl;
  int tid = threadIdx.x;
  int m = tid & 127, gb = (tid >> 7) * 2;
  int i_ = ip*2 + (m >> 6), j_ = m & 63;
  const float* Lrow = Hf + (size_t)tokrow(0, b, i_)*NH2;
  const float* Rrow = Hf + (size_t)tokrow(1, b, j_)*NH2;
  unsigned short* dst = CMT + ((size_t)(bl*32 + ip) * 16) * 4096;
  for (int kc = 0; kc < 16; kc++){
    int k0 = kc*32;
    #pragma unroll
    for (int gi = 0; gi < 2; gi++){
      int g = gb + gi;
      const float* lp = Lrow + k0 + g*8;
      const float* rp = Rrow + k0 + g*8;
      float4 l0 = *(const float4*)lp, l1 = *(const float4*)(lp+4);
      float4 r0 = *(const float4*)rp, r1 = *(const float4*)(rp+4);
      uint4 pk = { pack_bf16_rnd(fabsf(l0.x-r0.x), fabsf(l0.y-r0.y)),
                   pack_bf16_rnd(fabsf(l0.z-r0.z), fabsf(l0.w-r0.w)),
                   pack_bf16_rnd(fabsf(l1.x-r1.x), fabsf(l1.y-r1.y)),
                   pack_bf16_rnd(fabsf(l1.z-r1.z), fabsf(l1.w-r1.w)) };
      *(uint4*)&dst[kc*4096 + m*32 + TK_SWZ(g,m)*8] = pk;
    }
  }
}

// ---------------- token-matching scores via MFMA (DMA-staged tiles) ----------------
__global__ __launch_bounds__(256) void k_token_mfma(
    const unsigned short* __restrict__ CMT,  // [128 blk][16 kc][128][32] for this b-chunk
    const unsigned short* __restrict__ TW,   // [8][16][128][32]
    const float* __restrict__ bn, const float* __restrict__ bg,
    const float* __restrict__ lintW,
    float* __restrict__ P, int b0)
{
  __shared__ short Atile[4096];
  __shared__ short Btile[4096];
  __shared__ short Asave[8192];
  __shared__ float sred[256];
  int ip = blockIdx.x, bl = blockIdx.y, nc = blockIdx.z;
  int b = b0 + bl;
  int tid = threadIdx.x;
  int wave = tid >> 6, wm = wave >> 1, wn = wave & 1;
  int lane = tid & 63, l15 = lane & 15, lq = lane >> 4;

  const char* Ab = (const char*)(CMT + ((size_t)(bl*32 + ip) * 16) * 4096);
  const char* Bb = (const char*)(TW + ((size_t)(nc*16)) * 4096);

  f32x4 zero4 = {0.f,0.f,0.f,0.f};
  f32x4 acc[4][4];
  #pragma unroll
  for (int mi=0;mi<4;mi++)
    #pragma unroll
    for (int nj=0;nj<4;nj++) acc[mi][nj] = zero4;

  for (int kc = 0; kc < 16; kc++){
    const char* gA = Ab + (size_t)kc*8192;
    const char* gB = Bb + (size_t)kc*8192;
#if HAVE_GLLDS
    char* lA = (char*)Atile + wave*1024;
    char* lB = (char*)Btile + wave*1024;
    GLOAD_LDS16(gA + tid*16, lA);
    GLOAD_LDS16(gA + 4096 + tid*16, lA + 4096);
    GLOAD_LDS16(gB + tid*16, lB);
    GLOAD_LDS16(gB + 4096 + tid*16, lB + 4096);
    int cs = kc - 2*nc;
    if ((unsigned)cs < 2u){
      char* lS = (char*)Asave + cs*8192 + wave*1024;
      GLOAD_LDS16(gA + tid*16, lS);
      GLOAD_LDS16(gA + 4096 + tid*16, lS + 4096);
    }
#else
    {
      uint4 va0 = ((const uint4*)gA)[tid], va1 = ((const uint4*)gA)[256+tid];
      uint4 vb0 = ((const uint4*)gB)[tid], vb1 = ((const uint4*)gB)[256+tid];
      ((uint4*)Atile)[tid] = va0; ((uint4*)Atile)[256+tid] = va1;
      ((uint4*)Btile)[tid] = vb0; ((uint4*)Btile)[256+tid] = vb1;
      int cs = kc - 2*nc;
      if ((unsigned)cs < 2u){
        ((uint4*)Asave)[cs*512 + tid] = va0; ((uint4*)Asave)[cs*512 + 256+tid] = va1;
      }
    }
#endif
    __syncthreads();
    s16x8 af[4], bfv[4];
    #pragma unroll
    for (int mi=0;mi<4;mi++){
      int row = wm*64 + mi*16 + l15;
      af[mi] = *(const s16x8*)&Atile[row*32 + TK_SWZ(lq,row)*8];
    }
    #pragma unroll
    for (int nj=0;nj<4;nj++){
      int row = wn*64 + nj*16 + l15;
      bfv[nj] = *(const s16x8*)&Btile[row*32 + TK_SWZ(lq,row)*8];
    }
    #pragma unroll
    for (int mi=0;mi<4;mi++)
      #pragma unroll
      for (int nj=0;nj<4;nj++)
        acc[mi][nj] = __builtin_amdgcn_mfma_f32_16x16x32_bf16(af[mi], bfv[nj], acc[mi][nj], 0,0,0);
    __syncthreads();
  }

  // epilogue: pair an/ag via shfl_xor(1), highway + lint dot
  float bnv[4], bgv[4], lwv[4]; int qv[4];
  #pragma unroll
  for (int nj=0;nj<4;nj++){
    int q = (wn*64 + nj*16 + l15) >> 1;
    qv[nj] = q;
    int nf = nc*64 + q;
    bnv[nj] = bn[nf]; bgv[nj] = bg[nf]; lwv[nj] = lintW[nf];
  }
  float lmask = (l15 & 1) ? 0.f : 1.f;
  float sc[4][4];
  #pragma unroll
  for (int mi=0;mi<4;mi++)
    #pragma unroll
    for (int r=0;r<4;r++) sc[mi][r] = 0.f;

  #pragma unroll
  for (int nj=0;nj<4;nj++){
    int q = qv[nj];
    int cs = q >> 5, kk = q & 31, gor = kk >> 3, el = kk & 7;
    #pragma unroll
    for (int mi=0;mi<4;mi++){
      int mbase = wm*64 + mi*16 + lq*4;
      #pragma unroll
      for (int r=0;r<4;r++){
        float v  = acc[mi][nj][r];
        float pv = __shfl_xor(v, 1);
        int mm = mbase + r;
        unsigned short cu = (unsigned short)Asave[cs*4096 + mm*32 + TK_SWZ(gor,mm)*8 + el];
        float cmf = __uint_as_float(((unsigned int)cu) << 16);
        float an = v + bnv[nj];
        float ag = pv + bgv[nj];
        float gg = sigmoidf_(ag);
        float hw = fmaxf(an, 0.f)*gg + (1.f - gg)*cmf;
        sc[mi][r] += lmask * lwv[nj] * hw;
      }
    }
  }
  #pragma unroll
  for (int mi=0;mi<4;mi++)
    #pragma unroll
    for (int r=0;r<4;r++){
      float v = sc[mi][r];
      v += __shfl_xor(v, 1); v += __shfl_xor(v, 2);
      v += __shfl_xor(v, 4); v += __shfl_xor(v, 8);
      sc[mi][r] = v;
    }
  if (l15 == 0){
    #pragma unroll
    for (int mi=0;mi<4;mi++)
      #pragma unroll
      for (int r=0;r<4;r++)
        sred[(wm*64 + mi*16 + lq*4 + r)*2 + wn] = sc[mi][r];
  }
  __syncthreads();
  if (tid < 128){
    float v = sred[tid*2] + sred[tid*2+1];
    int isel = tid >> 6, j = tid & 63;
    P[(((size_t)nc*16 + b)*64 + (ip*2 + isel))*64 + j] = v;
  }
}

__global__ void k_score_reduce(const float* __restrict__ P, float* __restrict__ S){
  int idx = blockIdx.x*256 + threadIdx.x;  // 65536
  float v = 0.f;
  #pragma unroll
  for (int nc = 0; nc < 8; nc++) v += P[(size_t)nc*65536 + idx];
  S[idx] = v;
}

// ---------------- softmaxes over j (w_l) and over i (w_r) ----------------
__global__ void k_softmax_wl(const float* __restrict__ S, const float* __restrict__ TM,
                             float* __restrict__ WLo){
  int i = blockIdx.x, b = blockIdx.y, j = threadIdx.x;
  float mask = TM[1024 + b*64 + j];
  float v = S[((size_t)b*64 + i)*64 + j] + (mask != 0.f ? 0.f : -1e10f);
  float m = v;
  for (int o = 32; o; o >>= 1) m = fmaxf(m, __shfl_xor(m, o));
  float e = expf(v - m), s = e;
  for (int o = 32; o; o >>= 1) s += __shfl_xor(s, o);
  WLo[((size_t)b*64 + i)*64 + j] = e / s;
}
__global__ void k_softmax_wr(const float* __restrict__ S, const float* __restrict__ TM,
                             float* __restrict__ WRo){
  int j = blockIdx.x, b = blockIdx.y, i = threadIdx.x;
  float mask = TM[b*64 + i];
  float v = S[((size_t)b*64 + i)*64 + j] + (mask != 0.f ? 0.f : -1e10f);
  float m = v;
  for (int o = 32; o; o >>= 1) m = fmaxf(m, __shfl_xor(m, o));
  float e = expf(v - m), s = e;
  for (int o = 32; o; o >>= 1) s += __shfl_xor(s, o);
  WRo[((size_t)b*64 + j)*64 + i] = e / s;
}

// ---------------- weighted |L-R| sums ----------------
__global__ __launch_bounds__(256) void k_cmp(const float* __restrict__ Hf,
    const float* __restrict__ w, float* __restrict__ out, int side){
  int p = blockIdx.x, b = blockIdx.y;
  __shared__ float wl[64];
  if (threadIdx.x < 64) wl[threadIdx.x] = w[((size_t)b*64 + p)*64 + threadIdx.x];
  __syncthreads();
  int xr = tokrow(side, b, p);
  int d1 = threadIdx.x, d2 = threadIdx.x + 256;
  float x1 = Hf[(size_t)xr*NH2 + d1], x2 = Hf[(size_t)xr*NH2 + d2];
  float a1 = 0.f, a2 = 0.f;
  for (int q = 0; q < 64; q++){
    const float* yr = Hf + (size_t)tokrow(side^1, b, q)*NH2;
    float wq = wl[q];
    a1 += wq * fabsf(x1 - yr[d1]);
    a2 += wq * fabsf(x2 - yr[d2]);
  }
  out[((size_t)b*64 + p)*NH2 + d1] = a1;
  out[((size_t)b*64 + p)*NH2 + d2] = a2;
}

// ---------------- attribute matching -> concat buffer ----------------
__global__ __launch_bounds__(256) void k_attr(const float* __restrict__ Hf,
    const float* __restrict__ attrL, const float* __restrict__ attrR,
    const float* __restrict__ LC, const float* __restrict__ RC,
    const float* __restrict__ TM, const float* __restrict__ AM,
    const float* __restrict__ emptyA, float* __restrict__ CC){
  int fi = blockIdx.x, b = blockIdx.y, side = blockIdx.z;
  const float* attr = (side ? attrR : attrL) + fi*512;
  const float* cmp = side ? RC : LC;
  __shared__ float sc[32], wv[32];
  int t = threadIdx.x >> 3, l8 = threadIdx.x & 7;
  const float* er = Hf + (size_t)tokrow(side, b, fi*32 + t)*NH2;
  float acc = 0.f;
  for (int d = l8*64; d < l8*64 + 64; d++) acc += er[d]*attr[d];
  acc += __shfl_down(acc, 4, 8);
  acc += __shfl_down(acc, 2, 8);
  acc += __shfl_down(acc, 1, 8);
  if (l8 == 0) sc[t] = acc;
  __syncthreads();
  if (threadIdx.x < 32){
    float mask = TM[side*1024 + b*64 + fi*32 + threadIdx.x];
    float v = sc[threadIdx.x] + (mask != 0.f ? 0.f : -1e10f);
    float m = v;
    for (int o = 16; o; o >>= 1) m = fmaxf(m, __shfl_xor(m, o, 32));
    float e = expf(v - m), s = e;
    for (int o = 16; o; o >>= 1) s += __shfl_xor(s, o, 32);
    wv[threadIdx.x] = e / s;
  }
  __syncthreads();
  float am = AM[side*32 + b*2 + fi];
  int d1 = threadIdx.x, d2 = threadIdx.x + 256;
  float a1 = 0.f, a2 = 0.f;
  for (int t2 = 0; t2 < 32; t2++){
    float wq = wv[t2];
    const float* cr = cmp + ((size_t)b*64 + fi*32 + t2)*NH2;
    a1 += wq * cr[d1];
    a2 += wq * cr[d2];
  }
  float* dst = CC + (size_t)b*NDE + (size_t)(side*2 + fi)*512;
  dst[d1] = (am != 0.f) ? a1 : emptyA[d1];
  dst[d2] = (am != 0.f) ? a2 : emptyA[d2];
}

// ---------------- final highway (2048x2048) ----------------
__global__ __launch_bounds__(256) void k_final_hw(const float* __restrict__ X,
    const float* __restrict__ Wn, const float* __restrict__ bn,
    const float* __restrict__ Wg, const float* __restrict__ bg,
    float* __restrict__ HWo){
  __shared__ float Xs[4][2048];
  int nb = blockIdx.x, bq = blockIdx.y;
  for (int idx = threadIdx.x; idx < 8192; idx += 256)
    Xs[idx>>11][idx & 2047] = X[(size_t)(bq*4 + (idx>>11))*NDE + (idx & 2047)];
  __syncthreads();
  int nl = threadIdx.x >> 1, kl = threadIdx.x & 1;
  int n = nb*128 + nl;
  const float* wnr = Wn + (size_t)n*NDE + kl*1024;
  const float* wgr = Wg + (size_t)n*NDE + kl*1024;
  float an[4] = {0,0,0,0}, ag[4] = {0,0,0,0};
  for (int k = 0; k < 1024; k++){
    float wn = wnr[k], wg = wgr[k];
    int kk = kl*1024 + k;
    #pragma unroll
    for (int b4 = 0; b4 < 4; b4++){
      float xv = Xs[b4][kk];
      an[b4] = fmaf(wn, xv, an[b4]);
      ag[b4] = fmaf(wg, xv, ag[b4]);
    }
  }
  #pragma unroll
  for (int b4 = 0; b4 < 4; b4++){
    an[b4] += __shfl_down(an[b4], 1);
    ag[b4] += __shfl_down(ag[b4], 1);
  }
  if (kl == 0){
    float bnv = bn[n], bgv = bg[n];
    #pragma unroll
    for (int b4 = 0; b4 < 4; b4++){
      float a = an[b4] + bnv;
      float g = sigmoidf_(ag[b4] + bgv);
      float xv = Xs[b4][n];
      HWo[(size_t)(bq*4 + b4)*NDE + n] = fmaxf(a, 0.f)*g + (1.f - g)*xv;
    }
  }
}

// ---------------- linear + log_softmax ----------------
__global__ void k_out(const float* __restrict__ HWi, const float* __restrict__ lw,
                      const float* __restrict__ lb, float* __restrict__ out){
  int b = blockIdx.x, lane = threadIdx.x;
  float p0 = 0.f, p1 = 0.f;
  for (int n = lane; n < 2048; n += 64){
    float h = HWi[(size_t)b*NDE + n];
    p0 += h * lw[n];
    p1 += h * lw[2048 + n];
  }
  for (int o = 32; o; o >>= 1){ p0 += __shfl_xor(p0, o); p1 += __shfl_xor(p1, o); }
  if (lane == 0){
    float o0 = p0 + lb[0], o1 = p1 + lb[1];
    float m = fmaxf(o0, o1);
    float lse = m + logf(expf(o0 - m) + expf(o1 - m));
    out[b*2]   = o0 - lse;
    out[b*2+1] = o1 - lse;
  }
}

extern "C" void kernel_launch(void* const* d_in, const int* in_sizes, int n_in,
                              void* d_out, int out_size, void* d_ws, size_t ws_size,
                              hipStream_t stream){
  const float* lf0 = (const float*)d_in[0];
  const float* lf1 = (const float*)d_in[1];
  const float* rf0 = (const float*)d_in[2];
  const float* rf1 = (const float*)d_in[3];
  const float* gWih0 = (const float*)d_in[4];
  const float* gWhh0 = (const float*)d_in[5];
  const float* gbih0 = (const float*)d_in[6];
  const float* gbhh0 = (const float*)d_in[7];
  const float* gWih12 = (const float*)d_in[8];
  const float* gWhh12 = (const float*)d_in[9];
  const float* gbih12 = (const float*)d_in[10];
  const float* gbhh12 = (const float*)d_in[11];
  const float* hwtWn = (const float*)d_in[12];
  const float* hwtbn = (const float*)d_in[13];
  const float* hwtWg = (const float*)d_in[14];
  const float* hwtbg = (const float*)d_in[15];
  const float* lintW = (const float*)d_in[16];
  // d_in[17] = lintB (dropped: softmax is shift-invariant)
  const float* attrL = (const float*)d_in[18];
  const float* attrR = (const float*)d_in[19];
  const float* emptyA = (const float*)d_in[20];
  const float* hweWn = (const float*)d_in[21];
  const float* hwebn = (const float*)d_in[22];
  const float* hweWg = (const float*)d_in[23];
  const float* hwebg = (const float*)d_in[24];
  const float* lineW = (const float*)d_in[25];
  const float* lineB = (const float*)d_in[26];
  float* out = (float*)d_out;

  // ws layout: persistent region first, transient (X0/XI ∪ CMT) last. ~38 MB total.
  float* ws = (float*)d_ws;
  float* HA   = ws;                          // 1048576
  float* HB   = HA + 1048576;                // 1048576
  unsigned short* WHH = (unsigned short*)(HB + 1048576); // 1179648 shorts
  unsigned short* TW  = WHH + 1179648;       // 524288 shorts
  float* Sb   = (float*)(TW + 524288);       // 65536
  float* WLb  = Sb  + 65536;                 // 65536
  float* WRb  = WLb + 65536;                 // 65536
  float* LC   = WRb + 65536;                 // 524288
  float* RC   = LC + 524288;                 // 524288
  float* TM   = RC + 524288;                 // 2048
  float* AM   = TM + 2048;                   // 64
  float* CC   = AM + 64;                     // 32768
  float* HWb  = CC + 32768;                  // 32768
  float* P    = HWb + 32768;                 // 524288
  float* X0   = P + 524288;                  // 1572864
  float* XI   = X0 + 1572864;                // 3145728
  unsigned short* CMT = (unsigned short*)X0; // 8388608 shorts (16 MB) aliases X0+XI (dead after scans)

  k_gather<<<NBT, 256, 0, stream>>>(lf0, lf1, rf0, rf1, X0);
  k_masks<<<dim3(4,16), 256, 0, stream>>>(lf0, lf1, rf0, rf1, TM, AM);
  k_prep_whh<<<4608, 256, 0, stream>>>(gWhh0, gWhh12, WHH);
  k_prep_tw<<<2048, 256, 0, stream>>>(hwtWn, hwtWg, TW);

  // layer 0
  k_gemm_mfma<<<dim3(6,16,2), 256, 0, stream>>>(X0, gWih0, (long)NG3*NE, gbih0, NG3,
                                                XI, (long)NBT*NG3, NBT, NG3, NE);
  k_scan_mfma<<<dim3(4,2), 512, 0, stream>>>(XI, WHH, gbhh0, NG3, HA, 0);
  // layer 1
  k_gemm_mfma<<<dim3(6,16,2), 256, 0, stream>>>(HA, gWih12, (long)NG3*NH2, gbih12, NG3,
                                                XI, (long)NBT*NG3, NBT, NG3, NH2);
  k_scan_mfma<<<dim3(4,2), 512, 0, stream>>>(XI, WHH, gbhh12, NG3, HB, 2);
  // layer 2
  k_gemm_mfma<<<dim3(6,16,2), 256, 0, stream>>>(HB, gWih12 + (size_t)2*NG3*NH2, (long)NG3*NH2,
                                                gbih12 + 2*NG3, NG3,
                                                XI, (long)NBT*NG3, NBT, NG3, NH2);
  k_scan_mfma<<<dim3(4,2), 512, 0, stream>>>(XI, WHH, gbhh12 + 2*NG3, NG3, HA, 4);

  // token matching: 4 b-chunks of 4; CMT reused per chunk (stream-serialized)
  for (int c = 0; c < 4; c++){
    k_cm_pretile<<<dim3(32,4), 256, 0, stream>>>(HA, CMT, c*4);
    k_token_mfma<<<dim3(32,4,8), 256, 0, stream>>>(CMT, TW, hwtbn, hwtbg, lintW, P, c*4);
  }
  k_score_reduce<<<256, 256, 0, stream>>>(P, Sb);
  k_softmax_wl<<<dim3(64,16), 64, 0, stream>>>(Sb, TM, WLb);
  k_softmax_wr<<<dim3(64,16), 64, 0, stream>>>(Sb, TM, WRb);
  k_cmp<<<dim3(64,16), 256, 0, stream>>>(HA, WLb, LC, 0);
  k_cmp<<<dim3(64,16), 256, 0, stream>>>(HA, WRb, RC, 1);

  // attribute matching -> concat
  k_attr<<<dim3(2,16,2), 256, 0, stream>>>(HA, attrL, attrR, LC, RC, TM, AM, emptyA, CC);

  // final highway + classifier
  k_final_hw<<<dim3(16,4), 256, 0, stream>>>(CC, hweWn, hwebn, hweWg, hwebg, HWb);
  k_out<<<16, 64, 0, stream>>>(HWb, lineW, lineB, out);
}